// Round 14
// baseline (2274.286 us; speedup 1.0000x reference)
//
#include <hip/hip_runtime.h>
#include <hip/hip_bf16.h>

#define EPS 1e-5f

// ---------------------------------------------------------------------------
// MFMA ST-GCN, R14: conv split = taps 0-7 unpadded MFMA (K = 4c x 8taps,
// main loop CO/4 iters, was CO/2 with 7/16 zero-weight waste) + tap-8 as a
// 1x1 MFMA pass over c-innermost Gt (same machinery as the residual path).
//   G   : (n, CO, 18, Tr=TIN+16) bf16  t-innermost, 8-half t-guards
//   Gt  : (n, 18, Tr, CO) bf16         c-innermost, right t-guard [TIN,TIN+16)
//   B*  : (n, CO, 18, TOUT) bf16 ; Xt/Xm : (n, 18, T, C) bf16
// ugemmG/front1g dual-emit G+Gt (BN1+ReLU fused). NC=min(40, fit): chunk
// ~193MB stays L3-resident (R12: 332MB blew L3; R13: 179MB held, FETCH 56MB).
// fp32 accumulation everywhere.
// ---------------------------------------------------------------------------

typedef __attribute__((ext_vector_type(8))) short bf16x8;
typedef __attribute__((ext_vector_type(4))) float f32x4;
typedef __attribute__((ext_vector_type(4))) unsigned u32x4;

__device__ __forceinline__ unsigned short f2bf(float f) {
  unsigned u = __builtin_bit_cast(unsigned, f);
  u = (u + 0x7FFFu + ((u >> 16) & 1u)) >> 16;  // RNE, finite inputs
  return (unsigned short)u;
}
__device__ __forceinline__ float bf2f(unsigned short h) {
  unsigned u = (unsigned)h << 16;
  return __builtin_bit_cast(float, u);
}

// --------------------------- weight prep -----------------------------------

__global__ __launch_bounds__(256, 4) void k_transpose(
    const float* __restrict__ in, float* __restrict__ out, int rows, int cols) {
  int i = blockIdx.x * 256 + threadIdx.x;
  if (i < rows * cols) {
    int r = i / cols, c = i % cols;
    out[c * rows + r] = in[i];
  }
}

__global__ __launch_bounds__(256, 4) void k_beta(
    const float* __restrict__ bn2g, const float* __restrict__ bn2b,
    const float* __restrict__ tb, const float* __restrict__ rb,
    float* __restrict__ beta, int Co) {
  int o = blockIdx.x * 256 + threadIdx.x;
  if (o < Co)
    beta[o] = bn2g[o] * (1.0f / sqrtf(1.0f + EPS)) * tb[o] + bn2b[o] + rb[o];
}

__global__ __launch_bounds__(256, 4) void k_s1b1(
    const float* __restrict__ bn1g, const float* __restrict__ bn1b,
    const float* __restrict__ gb, float* __restrict__ s1v,
    float* __restrict__ b1p, int Co) {
  int o = blockIdx.x * 256 + threadIdx.x;
  if (o < Co) {
    float s1 = bn1g[o] * (1.0f / sqrtf(1.0f + EPS));
    s1v[o] = s1;
    b1p[o] = fmaf(s1, gb[o], bn1b[o]);
  }
}

// Conv A pack, taps 0-7: out[ot][kc][lane][8]; c = kc*4+q, tap = j (all valid)
__global__ __launch_bounds__(256, 4) void k_pack_conv8(
    const float* __restrict__ tw, const float* __restrict__ bn2g,
    unsigned short* __restrict__ out, int CO) {
  int total = (CO / 16) * (CO / 4) * 512;
  int i = blockIdx.x * 256 + threadIdx.x;
  if (i >= total) return;
  int j = i & 7, lane = (i >> 3) & 63, rest = i >> 9;
  int kc = rest % (CO / 4), ot = rest / (CO / 4);
  int q = lane >> 4, m = lane & 15;
  int c = kc * 4 + q, o = ot * 16 + m;
  out[i] = f2bf(tw[((size_t)o * CO + c) * 9 + j] * bn2g[o] * (1.0f / sqrtf(1.0f + EPS)));
}

// Tap-8 pack (K=c): out[ot][kc][lane][8], c = kc*32+q*8+j
__global__ __launch_bounds__(256, 4) void k_pack_tap8(
    const float* __restrict__ tw, const float* __restrict__ bn2g,
    unsigned short* __restrict__ out, int CO) {
  int total = (CO / 16) * (CO / 32) * 512;
  int i = blockIdx.x * 256 + threadIdx.x;
  if (i >= total) return;
  int j = i & 7, lane = (i >> 3) & 63, rest = i >> 9;
  int kc = rest % (CO / 32), ot = rest / (CO / 32);
  int q = lane >> 4, m = lane & 15;
  int c = kc * 32 + q * 8 + j, o = ot * 16 + m;
  out[i] = f2bf(tw[((size_t)o * CO + c) * 9 + 8] * bn2g[o] * (1.0f / sqrtf(1.0f + EPS)));
}

// K=c pack (residual rw / channel gw): out[ot][kc][lane][8], c = kc*32+q*8+j
__global__ __launch_bounds__(256, 4) void k_pack_k32(
    const float* __restrict__ W, unsigned short* __restrict__ out, int K, int M) {
  int total = (M / 16) * (K / 32) * 512;
  int i = blockIdx.x * 256 + threadIdx.x;
  if (i >= total) return;
  int j = i & 7, lane = (i >> 3) & 63, rest = i >> 9;
  int kc = rest % (K / 32), ot = rest / (K / 32);
  int q = lane >> 4, m = lane & 15;
  int c = kc * 32 + q * 8 + j, o = ot * 16 + m;
  out[i] = f2bf(W[(size_t)o * K + c]);
}

// --------------------------- block 1 front (fused) -------------------------
// data_bn -> A-mix -> 1x1 (2->64) -> BN1+ReLU -> G1 + Gt1; XB for residual.
__global__ __launch_bounds__(256, 4) void k_front1g(
    const float* __restrict__ x, const float* __restrict__ dbng,
    const float* __restrict__ dbnb, const float* __restrict__ Amat,
    const float* __restrict__ gw, const float* __restrict__ gb,
    const float* __restrict__ bn1g, const float* __restrict__ bn1b,
    unsigned short* __restrict__ G1, unsigned short* __restrict__ Gt1,
    float* __restrict__ xb1) {
  int n = blockIdx.x, t0 = blockIdx.y * 64;
  __shared__ float xb[2304];  // [c][tt][v]
  __shared__ float xm[2304];  // A-mixed
  __shared__ float As[324];
  const float rs = 1.0f / sqrtf(1.0f + EPS);
  for (int e = threadIdx.x; e < 324; e += 256) As[e] = Amat[e];
  for (int e = threadIdx.x; e < 2304; e += 256) {
    int c = e / 1152, r = e % 1152;  // r = tt*18+v
    int v = r % 18;
    xb[e] = x[(n * 2 + c) * 4608 + t0 * 18 + r] * (dbng[c * 18 + v] * rs) + dbnb[c * 18 + v];
  }
  __syncthreads();
  for (int e = threadIdx.x; e < 2304; e += 256) {
    int c = e / 1152, r = e % 1152;
    int v = r / 64, tt = r % 64;
    xb1[((size_t)(n * 2 + c) * 18 + v) * 256 + t0 + tt] = xb[c * 1152 + tt * 18 + v];
  }
  for (int e = threadIdx.x; e < 2304; e += 256) {
    int c = e / 1152, r = e % 1152;
    int tt = r / 18, v = r % 18;
    const float* xr = &xb[c * 1152 + tt * 18];
    float z = 0.0f;
#pragma unroll
    for (int w = 0; w < 18; w++) z = fmaf(As[v * 18 + w], xr[w], z);
    xm[e] = z;
  }
  __syncthreads();
  for (int e = threadIdx.x; e < 64 * 1152; e += 256) {
    int o = e / 1152, r = e % 1152;
    int v = r / 64, tt = r % 64;
    float s1 = bn1g[o] * rs;
    float g0 = gw[o * 2 + 0] * s1, g1 = gw[o * 2 + 1] * s1;
    float bp = fmaf(s1, gb[o], bn1b[o]);
    float z = fmaf(g0, xm[tt * 18 + v], fmaf(g1, xm[1152 + tt * 18 + v], bp));
    z = z > 0.0f ? z : 0.0f;
    int t = t0 + tt;
    unsigned short zb = f2bf(z);
    size_t row = ((size_t)(n * 64 + o) * 18 + v) * 272;
    G1[row + 8 + t] = zb;
    if (t < 8) G1[row + t] = 0;
    if (t >= 248) G1[row + t + 16] = 0;
    Gt1[((size_t)(n * 18 + v) * 272 + t) * 64 + o] = zb;
  }
  if (blockIdx.y == 3) {
    for (int e = threadIdx.x; e < 18 * 16 * 64; e += 256) {
      int v = e / 1024, r = e % 1024;
      int tg = 256 + r / 64, o = r % 64;
      Gt1[((size_t)(n * 18 + v) * 272 + tg) * 64 + o] = 0;
    }
  }
}

// --------------------------- A-mix on Xt -----------------------------------
template <int CO, int T>
__global__ __launch_bounds__(256, 4) void k_amixX(
    const unsigned short* __restrict__ Xt, unsigned short* __restrict__ Xm,
    const float* __restrict__ Amat) {
  int idx = blockIdx.x * 256 + threadIdx.x;
  int c = idx & (CO - 1);
  int t = (idx / CO) & (T - 1);
  int n = idx / (CO * T);
  const size_t stride = (size_t)T * CO;
  const unsigned short* bp = Xt + (size_t)n * 18 * stride + (size_t)t * CO + c;
  unsigned short* op = Xm + (size_t)n * 18 * stride + (size_t)t * CO + c;
  float xs[18];
#pragma unroll
  for (int w = 0; w < 18; w++) xs[w] = bf2f(bp[w * stride]);
#pragma unroll
  for (int v = 0; v < 18; v++) {
    float z = 0.0f;
#pragma unroll
    for (int w = 0; w < 18; w++) z = fmaf(Amat[v * 18 + w], xs[w], z);
    op[v * stride] = f2bf(z);
  }
}

// --------------------------- channel GEMM -> G + Gt (MFMA) -----------------
// G[n,o,v,8+t] / Gt[n,v,t,o] = relu(s1[o]*(gw·Xm) + b1p[o]); t/c guards set.
template <int CI, int CO, int TIN>
__global__ __launch_bounds__(64, 4) void k_ugemmG(
    const unsigned short* __restrict__ Xm, const unsigned short* __restrict__ Ag,
    const float* __restrict__ s1v, const float* __restrict__ b1p,
    unsigned short* __restrict__ G, unsigned short* __restrict__ Gt) {
  constexpr int NP = 18 * TIN;
  constexpr int Tr = TIN + 16;
  const int n = blockIdx.x;
  const int p0 = blockIdx.y * 32;
  const int otg = blockIdx.z;  // 2 o-tiles of 16
  const int lane = threadIdx.x;
  const int q = lane >> 4, nn = lane & 15;
  constexpr int KC = CI / 32;
  const int v = p0 / TIN;
  const int tb = p0 % TIN;
  f32x4 acc[2][2] = {};
  const unsigned short* Xn = Xm + (size_t)n * NP * CI;
  for (int kc = 0; kc < KC; kc++) {
    bf16x8 A[2];
#pragma unroll
    for (int i = 0; i < 2; i++)
      A[i] = *(const bf16x8*)(Ag + (((size_t)(otg * 2 + i) * KC + kc) * 64 + lane) * 8);
#pragma unroll
    for (int u = 0; u < 2; u++) {
      bf16x8 B = *(const bf16x8*)(Xn + (size_t)(p0 + u * 16 + nn) * CI + kc * 32 + q * 8);
#pragma unroll
      for (int i = 0; i < 2; i++)
        acc[i][u] = __builtin_amdgcn_mfma_f32_16x16x32_bf16(A[i], B, acc[i][u], 0, 0, 0);
    }
  }
#pragma unroll
  for (int i = 0; i < 2; i++) {
    int ob = (otg * 2 + i) * 16 + q * 4;
    const float4 s4 = *(const float4*)&s1v[ob];
    const float4 b4 = *(const float4*)&b1p[ob];
#pragma unroll
    for (int u = 0; u < 2; u++) {
      int t = tb + u * 16 + nn;
      unsigned short zb[4];
#pragma unroll
      for (int r = 0; r < 4; r++) {
        float z = fmaf(acc[i][u][r], ((const float*)&s4)[r], ((const float*)&b4)[r]);
        z = z > 0.0f ? z : 0.0f;
        zb[r] = f2bf(z);
        G[((size_t)(n * CO + ob + r) * 18 + v) * Tr + 8 + t] = zb[r];
      }
      *(unsigned long long*)&Gt[((size_t)(n * 18 + v) * Tr + t) * CO + ob] =
          *(const unsigned long long*)zb;
    }
  }
  // guards: left/right t-guards of G rows; right t-guard of Gt
  if (tb == 0) {
    int oh = otg * 32 + (lane >> 1), j0 = (lane & 1) * 4;
    size_t row = ((size_t)(n * CO + oh) * 18 + v) * Tr;
#pragma unroll
    for (int j = 0; j < 4; j++) G[row + j0 + j] = 0;
    for (int g = 0; g < 8; g++) {
      int idx = g * 64 + lane;  // 512 = 16t x 32c
      int tg = TIN + (idx >> 5), c = otg * 32 + (idx & 31);
      Gt[((size_t)(n * 18 + v) * Tr + tg) * CO + c] = 0;
    }
  }
  if (tb == TIN - 32) {
    int oh = otg * 32 + (lane >> 1), j0 = (lane & 1) * 4;
    size_t row = ((size_t)(n * CO + oh) * 18 + v) * Tr + 8 + TIN;
#pragma unroll
    for (int j = 0; j < 4; j++) G[row + j0 + j] = 0;
  }
}

// --------------------------- fused conv (MFMA, prefetched) -----------------
// main: taps 0-7, K = 4c x 8taps; tap8: 1x1 over Gt; residual: 1x1 over Xt.
template <int CIN, int CO, int S, int TIN, int TOUT, int OTB, int TB>
__global__ __launch_bounds__(64, 4) void k_conv(
    const unsigned short* __restrict__ G, const unsigned short* __restrict__ Gt,
    const unsigned short* __restrict__ Xt, const float* __restrict__ XB,
    const unsigned short* __restrict__ Ac, const unsigned short* __restrict__ At8,
    const unsigned short* __restrict__ Ar, const float* __restrict__ rwT1,
    const float* __restrict__ beta, unsigned short* __restrict__ Out) {
  constexpr int Tr = TIN + 16;
  constexpr int KC = CO / 4;   // main-loop iterations (4c x 8taps per K=32)
  constexpr int KT8 = CO / 32; // tap-8 iterations
  constexpr int KCR = (CIN >= 32) ? CIN / 32 : 0;
  constexpr int OT2 = CO / (16 * OTB);
  const int n = blockIdx.x;
  const int to_base = blockIdx.y * (16 * TB);
  const int z = blockIdx.z;
  const int otg = z % OT2;
  const int v0 = (z / OT2) * 2;
  const int lane = threadIdx.x;
  const int q = lane >> 4, nn = lane & 15;

  f32x4 acc[OTB][TB][2] = {};

  const unsigned* Gu = (const unsigned*)G;
  // c = kc*4 + q ; per-lane K-run = taps 0..7 = 8 consecutive t from S*to-4
  size_t h_tu[TB][2];
#pragma unroll
  for (int tb = 0; tb < TB; tb++)
#pragma unroll
    for (int u = 0; u < 2; u++) {
      int t0h = S * (to_base + tb * 16 + nn) - 4;
      h_tu[tb][u] = ((size_t)n * CO + q) * (18 * Tr) + (size_t)(v0 + u) * Tr + 8 +
                    (size_t)(long)t0h;
    }

  const unsigned short* Acp = Ac + ((size_t)otg * OTB * KC * 64 + lane) * 8;

  auto loadA = [&](int kc, bf16x8* A) {
#pragma unroll
    for (int i = 0; i < OTB; i++)
      A[i] = *(const bf16x8*)(Acp + ((size_t)i * KC + kc) * 512);
  };
  auto loadB = [&](int kc, bf16x8 (*B)[2]) {
#pragma unroll
    for (int tb = 0; tb < TB; tb++)
#pragma unroll
      for (int u = 0; u < 2; u++) {
        size_t h = h_tu[tb][u] + (size_t)kc * (4 * 18 * Tr);
        union { u32x4 d4; unsigned d[4]; bf16x8 v; } bb;
        if (S == 2) {
          bb.d4 = *(const u32x4*)(Gu + (h >> 1));  // h even for S=2
        } else {
          const unsigned* p = Gu + (h >> 1);
          u32x4 dd = *(const u32x4*)p;
          unsigned d4 = p[4];
          if (h & 1) {
            bb.d[0] = (dd.x >> 16) | (dd.y << 16); bb.d[1] = (dd.y >> 16) | (dd.z << 16);
            bb.d[2] = (dd.z >> 16) | (dd.w << 16); bb.d[3] = (dd.w >> 16) | (d4 << 16);
          } else {
            bb.d4 = dd;
          }
        }
        B[tb][u] = bb.v;
      }
  };

  bf16x8 Acur[OTB], Bcur[TB][2];
  loadA(0, Acur);
  loadB(0, Bcur);
  for (int kc = 0; kc < KC; kc++) {
    bf16x8 Anx[OTB], Bnx[TB][2];
    const int kn = (kc + 1 < KC) ? kc + 1 : kc;
    loadA(kn, Anx);
    loadB(kn, Bnx);
#pragma unroll
    for (int i = 0; i < OTB; i++)
#pragma unroll
      for (int tb = 0; tb < TB; tb++)
#pragma unroll
        for (int u = 0; u < 2; u++)
          acc[i][tb][u] =
              __builtin_amdgcn_mfma_f32_16x16x32_bf16(Acur[i], Bcur[tb][u], acc[i][tb][u],
                                                      0, 0, 0);
#pragma unroll
    for (int i = 0; i < OTB; i++) Acur[i] = Anx[i];
#pragma unroll
    for (int tb = 0; tb < TB; tb++)
#pragma unroll
      for (int u = 0; u < 2; u++) Bcur[tb][u] = Bnx[tb][u];
  }

  // ---- tap 8: 1x1 over Gt at ti = S*to + 4 (right guard covers overrun) ----
  for (int k8 = 0; k8 < KT8; k8++) {
    bf16x8 A[OTB];
#pragma unroll
    for (int i = 0; i < OTB; i++)
      A[i] = *(const bf16x8*)(At8 + (((size_t)(otg * OTB + i) * KT8 + k8) * 64 + lane) * 8);
#pragma unroll
    for (int tb = 0; tb < TB; tb++)
#pragma unroll
      for (int u = 0; u < 2; u++) {
        int ti = S * (to_base + tb * 16 + nn) + 4;
        bf16x8 B = *(const bf16x8*)(Gt + (((size_t)n * 18 + v0 + u) * Tr + ti) * CO +
                                    k8 * 32 + q * 8);
#pragma unroll
        for (int i = 0; i < OTB; i++)
          acc[i][tb][u] =
              __builtin_amdgcn_mfma_f32_16x16x32_bf16(A[i], B, acc[i][tb][u], 0, 0, 0);
      }
  }

  if (CIN >= 32) {
    for (int kcr = 0; kcr < KCR; kcr++) {
      bf16x8 A[OTB];
#pragma unroll
      for (int i = 0; i < OTB; i++)
        A[i] = *(const bf16x8*)(Ar + (((size_t)(otg * OTB + i) * KCR + kcr) * 64 + lane) * 8);
#pragma unroll
      for (int tb = 0; tb < TB; tb++)
#pragma unroll
        for (int u = 0; u < 2; u++) {
          int t = S * (to_base + tb * 16 + nn);
          bf16x8 B = *(const bf16x8*)(Xt + (((size_t)n * 18 + v0 + u) * TIN + t) * CIN +
                                      kcr * 32 + q * 8);
#pragma unroll
          for (int i = 0; i < OTB; i++)
            acc[i][tb][u] =
                __builtin_amdgcn_mfma_f32_16x16x32_bf16(A[i], B, acc[i][tb][u], 0, 0, 0);
        }
    }
  } else {
#pragma unroll
    for (int ci = 0; ci < 2; ci++) {
#pragma unroll
      for (int tb = 0; tb < TB; tb++)
#pragma unroll
        for (int u = 0; u < 2; u++) {
          float xv =
              XB[(((size_t)n * 2 + ci) * 18 + v0 + u) * TIN + S * (to_base + tb * 16 + nn)];
#pragma unroll
          for (int i = 0; i < OTB; i++) {
            const float4 w4 = *(const float4*)&rwT1[ci * CO + (otg * OTB + i) * 16 + q * 4];
            acc[i][tb][u][0] = fmaf(w4.x, xv, acc[i][tb][u][0]);
            acc[i][tb][u][1] = fmaf(w4.y, xv, acc[i][tb][u][1]);
            acc[i][tb][u][2] = fmaf(w4.z, xv, acc[i][tb][u][2]);
            acc[i][tb][u][3] = fmaf(w4.w, xv, acc[i][tb][u][3]);
          }
        }
    }
  }

#pragma unroll
  for (int i = 0; i < OTB; i++) {
    int ob = (otg * OTB + i) * 16 + q * 4;
    const float4 bt = *(const float4*)&beta[ob];
#pragma unroll
    for (int tb = 0; tb < TB; tb++)
#pragma unroll
      for (int u = 0; u < 2; u++) {
        int v = v0 + u, to = to_base + tb * 16 + nn;
#pragma unroll
        for (int r = 0; r < 4; r++) {
          float val = acc[i][tb][u][r] + ((const float*)&bt)[r];
          Out[(((size_t)n * CO + ob + r) * 18 + v) * TOUT + to] =
              f2bf(val > 0.0f ? val : 0.0f);
        }
      }
  }
}

// ------------- EMA smooth (bf16 in) -> bf16 transposed emission ------------
__global__ __launch_bounds__(64) void k_smooth2(
    const unsigned short* __restrict__ X, unsigned short* __restrict__ Xt,
    int CO, int T) {
  __shared__ float tile[64 * 33];
  int n = blockIdx.x, v = blockIdx.y, c0 = blockIdx.z * 64;
  int tid = threadIdx.x;
  float s = 0.0f;
  for (int tc = 0; tc < T; tc += 32) {
    for (int e = tid; e < 64 * 32; e += 64) {
      int cc = e >> 5, tt = e & 31;
      tile[cc * 33 + tt] = bf2f(X[((size_t)(n * CO + c0 + cc) * 18 + v) * T + tc + tt]);
    }
    __syncthreads();
    float* row = &tile[tid * 33];
    int start = 0;
    if (tc == 0) { s = row[0]; start = 1; }
    for (int tt = start; tt < 32; tt++) {
      s = fmaf(0.85f, s, 0.15f * row[tt]);
      row[tt] = s;
    }
    for (int it = 0; it < 32; it++)
      Xt[((size_t)(n * 18 + v) * T + tc + it) * CO + c0 + tid] = f2bf(tile[tid * 33 + it]);
    __syncthreads();
  }
}

// in-place EMA on bf16 rows (block 3); rows contiguous length T.
__global__ __launch_bounds__(64) void k_smooth(unsigned short* __restrict__ X, int T) {
  __shared__ float tile[64 * 33];
  size_t r0 = (size_t)blockIdx.x * 64;
  float s = 0.0f;
  for (int tc = 0; tc < T; tc += 32) {
    for (int e = threadIdx.x; e < 64 * 32; e += 64) {
      int r = e >> 5, tt = e & 31;
      tile[r * 33 + tt] = bf2f(X[(r0 + r) * T + tc + tt]);
    }
    __syncthreads();
    float* row = &tile[threadIdx.x * 33];
    int start = 0;
    if (tc == 0) { s = row[0]; start = 1; }
    for (int tt = start; tt < 32; tt++) {
      s = fmaf(0.85f, s, 0.15f * row[tt]);
      row[tt] = s;
    }
    __syncthreads();
    for (int e = threadIdx.x; e < 64 * 32; e += 64) {
      int r = e >> 5, tt = e & 31;
      X[(r0 + r) * T + tc + tt] = f2bf(tile[r * 33 + tt]);
    }
    __syncthreads();
  }
}

// mean over (v,t)=1152 then 10-way FC.  H:(nc,256,18,64) bf16
__global__ __launch_bounds__(256, 4) void k_poolfc(
    const unsigned short* __restrict__ H, const float* __restrict__ fcw,
    const float* __restrict__ fcb, float* __restrict__ out) {
  int n = blockIdx.x;
  __shared__ float pool[256];
  const unsigned short* row = H + (size_t)(n * 256 + threadIdx.x) * 1152;
  float s = 0.0f;
  for (int i = 0; i < 1152; i += 8) {
    u32x4 d = *(const u32x4*)(row + i);
#pragma unroll
    for (int k = 0; k < 4; k++) {
      unsigned dv = ((const unsigned*)&d)[k];
      s += __builtin_bit_cast(float, dv << 16);
      s += __builtin_bit_cast(float, dv & 0xFFFF0000u);
    }
  }
  pool[threadIdx.x] = s * (1.0f / 1152.0f);
  __syncthreads();
  if (threadIdx.x < 10) {
    float a = fcb[threadIdx.x];
    for (int c = 0; c < 256; c++) a = fmaf(fcw[threadIdx.x * 256 + c], pool[c], a);
    out[n * 10 + threadIdx.x] = a;
  }
}

extern "C" void kernel_launch(void* const* d_in, const int* in_sizes, int n_in,
                              void* d_out, int out_size, void* d_ws, size_t ws_size,
                              hipStream_t stream) {
  const float* x    = (const float*)d_in[0];
  const float* Amat = (const float*)d_in[1];
  const float* dbng = (const float*)d_in[2];
  const float* dbnb = (const float*)d_in[3];
  const float* gw1 = (const float*)d_in[4];   const float* gb1 = (const float*)d_in[5];
  const float* bn1g1 = (const float*)d_in[6]; const float* bn1b1 = (const float*)d_in[7];
  const float* tw1 = (const float*)d_in[8];   const float* tb1 = (const float*)d_in[9];
  const float* bn2g1 = (const float*)d_in[10]; const float* bn2b1 = (const float*)d_in[11];
  const float* rw1 = (const float*)d_in[12];  const float* rb1 = (const float*)d_in[13];
  const float* gw2 = (const float*)d_in[14];  const float* gb2 = (const float*)d_in[15];
  const float* bn1g2 = (const float*)d_in[16]; const float* bn1b2 = (const float*)d_in[17];
  const float* tw2 = (const float*)d_in[18];  const float* tb2 = (const float*)d_in[19];
  const float* bn2g2 = (const float*)d_in[20]; const float* bn2b2 = (const float*)d_in[21];
  const float* rw2 = (const float*)d_in[22];  const float* rb2 = (const float*)d_in[23];
  const float* gw3 = (const float*)d_in[24];  const float* gb3 = (const float*)d_in[25];
  const float* bn1g3 = (const float*)d_in[26]; const float* bn1b3 = (const float*)d_in[27];
  const float* tw3 = (const float*)d_in[28];  const float* tb3 = (const float*)d_in[29];
  const float* bn2g3 = (const float*)d_in[30]; const float* bn2b3 = (const float*)d_in[31];
  const float* rw3 = (const float*)d_in[32];  const float* rb3 = (const float*)d_in[33];
  const float* fcw = (const float*)d_in[34];  const float* fcb = (const float*)d_in[35];
  (void)in_sizes; (void)n_in; (void)out_size;

  // ---- weights region at ws base ----
  float* f = (float*)d_ws;
  float* rwT1  = f;             // 128
  float* beta1 = rwT1 + 128;    // 64
  float* beta2 = beta1 + 64;    // 128
  float* beta3 = beta2 + 128;   // 256
  float* s1v2  = beta3 + 256;   // 128
  float* b1p2  = s1v2 + 128;    // 128
  float* s1v3  = b1p2 + 128;    // 256
  float* b1p3  = s1v3 + 256;    // 256
  // pad to 2048 floats
  unsigned short* H = (unsigned short*)(f + 2048);
  unsigned short* Ac1 = H;                 // 32768   (64^2*8)
  unsigned short* Ac2 = Ac1 + 32768;       // 131072  (128^2*8)
  unsigned short* Ac3 = Ac2 + 131072;      // 524288  (256^2*8)
  unsigned short* At1 = Ac3 + 524288;      // 4096
  unsigned short* At2 = At1 + 4096;        // 16384
  unsigned short* At3 = At2 + 16384;       // 65536
  unsigned short* Ar2 = At3 + 65536;       // 8192
  unsigned short* Ar3 = Ar2 + 8192;        // 32768
  unsigned short* Ag2 = Ar3 + 32768;       // 8192
  unsigned short* Ag3 = Ag2 + 8192;        // 32768
  const size_t WOFFB = 8192 + 856064ULL * 2;  // 1,720,320 bytes (16B aligned)

  // ---- NC = min(40, floor(avail/per_n)) : chunk <= ~193 MB (L3-resident) --
  // per-n bytes: B1 589824 + B2 589824 + XB 36864 + G 1327104 + Gt 1327104
  //            + Xt 589824 + Xm 589824 = 5,050,368
  const size_t PERN = 5050368ULL;
  long long avail = (long long)ws_size - (long long)WOFFB - 256;
  int NC = (avail > 0) ? (int)(avail / (long long)PERN) : 1;
  if (NC > 40) NC = 40;
  if (NC < 1) NC = 1;
  char* wb = (char*)d_ws;
  unsigned short* B1 = (unsigned short*)(wb + WOFFB);
  unsigned short* B2 = B1 + (size_t)NC * 294912;
  float* XB = (float*)((char*)B2 + (size_t)NC * 589824);
  unsigned short* G  = (unsigned short*)((char*)XB + (size_t)NC * 36864);
  unsigned short* Gt = (unsigned short*)((char*)G + (size_t)NC * 1327104);
  unsigned short* Xt = (unsigned short*)((char*)Gt + (size_t)NC * 1327104);
  unsigned short* Xm = Xt + (size_t)NC * 294912;

  // ---- weight prep (idempotent) ----
  k_transpose<<<1, 256, 0, stream>>>(rw1, rwT1, 64, 2);
  k_beta<<<1, 256, 0, stream>>>(bn2g1, bn2b1, tb1, rb1, beta1, 64);
  k_beta<<<1, 256, 0, stream>>>(bn2g2, bn2b2, tb2, rb2, beta2, 128);
  k_beta<<<1, 256, 0, stream>>>(bn2g3, bn2b3, tb3, rb3, beta3, 256);
  k_s1b1<<<1, 256, 0, stream>>>(bn1g2, bn1b2, gb2, s1v2, b1p2, 128);
  k_s1b1<<<1, 256, 0, stream>>>(bn1g3, bn1b3, gb3, s1v3, b1p3, 256);
  k_pack_conv8<<<128, 256, 0, stream>>>(tw1, bn2g1, Ac1, 64);
  k_pack_conv8<<<512, 256, 0, stream>>>(tw2, bn2g2, Ac2, 128);
  k_pack_conv8<<<2048, 256, 0, stream>>>(tw3, bn2g3, Ac3, 256);
  k_pack_tap8<<<16, 256, 0, stream>>>(tw1, bn2g1, At1, 64);
  k_pack_tap8<<<64, 256, 0, stream>>>(tw2, bn2g2, At2, 128);
  k_pack_tap8<<<256, 256, 0, stream>>>(tw3, bn2g3, At3, 256);
  k_pack_k32<<<32, 256, 0, stream>>>(rw2, Ar2, 64, 128);
  k_pack_k32<<<128, 256, 0, stream>>>(rw3, Ar3, 128, 256);
  k_pack_k32<<<32, 256, 0, stream>>>(gw2, Ag2, 64, 128);
  k_pack_k32<<<128, 256, 0, stream>>>(gw3, Ag3, 128, 256);

  // ---- network per N-chunk (ragged) ----
  for (int n0 = 0; n0 < 128; n0 += NC) {
    const int nc = (128 - n0 < NC) ? 128 - n0 : NC;
    // block 1
    k_front1g<<<dim3(nc, 4), 256, 0, stream>>>(
        x + (size_t)n0 * 9216, dbng, dbnb, Amat, gw1, gb1, bn1g1, bn1b1, G, Gt, XB);
    k_conv<2, 64, 1, 256, 256, 4, 2><<<dim3(nc, 8, 9), 64, 0, stream>>>(
        G, Gt, nullptr, XB, Ac1, At1, nullptr, rwT1, beta1, B1);
    k_smooth2<<<dim3(nc, 18, 1), 64, 0, stream>>>(B1, Xt, 64, 256);
    // block 2
    k_amixX<64, 256><<<nc * 64, 256, 0, stream>>>(Xt, Xm, Amat);
    k_ugemmG<64, 128, 256><<<dim3(nc, 144, 4), 64, 0, stream>>>(
        Xm, Ag2, s1v2, b1p2, G, Gt);
    k_conv<64, 128, 2, 256, 128, 4, 2><<<dim3(nc, 4, 18), 64, 0, stream>>>(
        G, Gt, Xt, nullptr, Ac2, At2, Ar2, nullptr, beta2, B2);
    k_smooth2<<<dim3(nc, 18, 2), 64, 0, stream>>>(B2, Xt, 128, 128);
    // block 3 (output reuses B1)
    k_amixX<128, 128><<<nc * 64, 256, 0, stream>>>(Xt, Xm, Amat);
    k_ugemmG<128, 256, 128><<<dim3(nc, 72, 8), 64, 0, stream>>>(
        Xm, Ag3, s1v3, b1p3, G, Gt);
    k_conv<128, 256, 2, 128, 64, 4, 2><<<dim3(nc, 2, 36), 64, 0, stream>>>(
        G, Gt, Xt, nullptr, Ac3, At3, Ar3, nullptr, beta3, B1);
    k_smooth<<<nc * 72, 64, 0, stream>>>(B1, 64);
    // head
    k_poolfc<<<nc, 256, 0, stream>>>(B1, fcw, fcb, (float*)d_out + (size_t)n0 * 10);
  }
}

// Round 15
// 1831.650 us; speedup vs baseline: 1.2417x; 1.2417x over previous
//
#include <hip/hip_runtime.h>
#include <hip/hip_bf16.h>

#define EPS 1e-5f

// ---------------------------------------------------------------------------
// MFMA ST-GCN, R15 = R14 (split-tap conv: taps 0-7 unpadded MFMA K=4cx8taps +
// tap-8 as 1x1 over c-innermost Gt) with COALESCED Gt emission:
// R14's Gt writes were 2-8B scatters at 128-256B stride -> 16x HBM write
// amplification (front1g WRITE_SIZE 800MB, 185us). R15 stages output tiles in
// LDS and writes Gt with lanes along c (full 64B lines).
//   G   : (n, CO, 18, Tr=TIN+16) bf16  t-innermost, 8-half t-guards
//   Gt  : (n, 18, Tr, CO) bf16         c-innermost, right t-guard [TIN,TIN+16)
//   B*  : (n, CO, 18, TOUT) bf16 ; Xt/Xm : (n, 18, T, C) bf16
// NC=min(40, fit) keeps chunk ~200MB L3-resident. fp32 accumulation.
// ---------------------------------------------------------------------------

typedef __attribute__((ext_vector_type(8))) short bf16x8;
typedef __attribute__((ext_vector_type(4))) float f32x4;
typedef __attribute__((ext_vector_type(4))) unsigned u32x4;

__device__ __forceinline__ unsigned short f2bf(float f) {
  unsigned u = __builtin_bit_cast(unsigned, f);
  u = (u + 0x7FFFu + ((u >> 16) & 1u)) >> 16;  // RNE, finite inputs
  return (unsigned short)u;
}
__device__ __forceinline__ float bf2f(unsigned short h) {
  unsigned u = (unsigned)h << 16;
  return __builtin_bit_cast(float, u);
}

// --------------------------- weight prep -----------------------------------

__global__ __launch_bounds__(256, 4) void k_transpose(
    const float* __restrict__ in, float* __restrict__ out, int rows, int cols) {
  int i = blockIdx.x * 256 + threadIdx.x;
  if (i < rows * cols) {
    int r = i / cols, c = i % cols;
    out[c * rows + r] = in[i];
  }
}

__global__ __launch_bounds__(256, 4) void k_beta(
    const float* __restrict__ bn2g, const float* __restrict__ bn2b,
    const float* __restrict__ tb, const float* __restrict__ rb,
    float* __restrict__ beta, int Co) {
  int o = blockIdx.x * 256 + threadIdx.x;
  if (o < Co)
    beta[o] = bn2g[o] * (1.0f / sqrtf(1.0f + EPS)) * tb[o] + bn2b[o] + rb[o];
}

__global__ __launch_bounds__(256, 4) void k_s1b1(
    const float* __restrict__ bn1g, const float* __restrict__ bn1b,
    const float* __restrict__ gb, float* __restrict__ s1v,
    float* __restrict__ b1p, int Co) {
  int o = blockIdx.x * 256 + threadIdx.x;
  if (o < Co) {
    float s1 = bn1g[o] * (1.0f / sqrtf(1.0f + EPS));
    s1v[o] = s1;
    b1p[o] = fmaf(s1, gb[o], bn1b[o]);
  }
}

// Conv A pack, taps 0-7: out[ot][kc][lane][8]; c = kc*4+q, tap = j (all valid)
__global__ __launch_bounds__(256, 4) void k_pack_conv8(
    const float* __restrict__ tw, const float* __restrict__ bn2g,
    unsigned short* __restrict__ out, int CO) {
  int total = (CO / 16) * (CO / 4) * 512;
  int i = blockIdx.x * 256 + threadIdx.x;
  if (i >= total) return;
  int j = i & 7, lane = (i >> 3) & 63, rest = i >> 9;
  int kc = rest % (CO / 4), ot = rest / (CO / 4);
  int q = lane >> 4, m = lane & 15;
  int c = kc * 4 + q, o = ot * 16 + m;
  out[i] = f2bf(tw[((size_t)o * CO + c) * 9 + j] * bn2g[o] * (1.0f / sqrtf(1.0f + EPS)));
}

// Tap-8 pack (K=c): out[ot][kc][lane][8], c = kc*32+q*8+j
__global__ __launch_bounds__(256, 4) void k_pack_tap8(
    const float* __restrict__ tw, const float* __restrict__ bn2g,
    unsigned short* __restrict__ out, int CO) {
  int total = (CO / 16) * (CO / 32) * 512;
  int i = blockIdx.x * 256 + threadIdx.x;
  if (i >= total) return;
  int j = i & 7, lane = (i >> 3) & 63, rest = i >> 9;
  int kc = rest % (CO / 32), ot = rest / (CO / 32);
  int q = lane >> 4, m = lane & 15;
  int c = kc * 32 + q * 8 + j, o = ot * 16 + m;
  out[i] = f2bf(tw[((size_t)o * CO + c) * 9 + 8] * bn2g[o] * (1.0f / sqrtf(1.0f + EPS)));
}

// K=c pack (residual rw / channel gw): out[ot][kc][lane][8], c = kc*32+q*8+j
__global__ __launch_bounds__(256, 4) void k_pack_k32(
    const float* __restrict__ W, unsigned short* __restrict__ out, int K, int M) {
  int total = (M / 16) * (K / 32) * 512;
  int i = blockIdx.x * 256 + threadIdx.x;
  if (i >= total) return;
  int j = i & 7, lane = (i >> 3) & 63, rest = i >> 9;
  int kc = rest % (K / 32), ot = rest / (K / 32);
  int q = lane >> 4, m = lane & 15;
  int c = kc * 32 + q * 8 + j, o = ot * 16 + m;
  out[i] = f2bf(W[(size_t)o * K + c]);
}

// --------------------------- block 1 front (fused) -------------------------
// data_bn -> A-mix -> 1x1 (2->64) -> BN1+ReLU -> G1 + Gt1 (LDS-transposed,
// coalesced); XB for residual.
__global__ __launch_bounds__(256, 4) void k_front1g(
    const float* __restrict__ x, const float* __restrict__ dbng,
    const float* __restrict__ dbnb, const float* __restrict__ Amat,
    const float* __restrict__ gw, const float* __restrict__ gb,
    const float* __restrict__ bn1g, const float* __restrict__ bn1b,
    unsigned short* __restrict__ G1, unsigned short* __restrict__ Gt1,
    float* __restrict__ xb1) {
  int n = blockIdx.x, t0 = blockIdx.y * 64;
  __shared__ float xb[2304];  // [c][tt][v]
  __shared__ float xm[2304];  // A-mixed
  __shared__ float As[324];
  __shared__ float g0s[64], g1s[64], bps[64];
  __shared__ unsigned short ldsT[64 * 65];  // [o][tt], pad 65
  const float rs = 1.0f / sqrtf(1.0f + EPS);
  for (int e = threadIdx.x; e < 324; e += 256) As[e] = Amat[e];
  if (threadIdx.x < 64) {
    int o = threadIdx.x;
    float s1 = bn1g[o] * rs;
    g0s[o] = gw[o * 2 + 0] * s1;
    g1s[o] = gw[o * 2 + 1] * s1;
    bps[o] = fmaf(s1, gb[o], bn1b[o]);
  }
  for (int e = threadIdx.x; e < 2304; e += 256) {
    int c = e / 1152, r = e % 1152;  // r = tt*18+v
    int v = r % 18;
    xb[e] = x[(n * 2 + c) * 4608 + t0 * 18 + r] * (dbng[c * 18 + v] * rs) + dbnb[c * 18 + v];
  }
  __syncthreads();
  for (int e = threadIdx.x; e < 2304; e += 256) {
    int c = e / 1152, r = e % 1152;
    int v = r / 64, tt = r % 64;
    xb1[((size_t)(n * 2 + c) * 18 + v) * 256 + t0 + tt] = xb[c * 1152 + tt * 18 + v];
  }
  for (int e = threadIdx.x; e < 2304; e += 256) {
    int c = e / 1152, r = e % 1152;
    int tt = r / 18, v = r % 18;
    const float* xr = &xb[c * 1152 + tt * 18];
    float z = 0.0f;
#pragma unroll
    for (int w = 0; w < 18; w++) z = fmaf(As[v * 18 + w], xr[w], z);
    xm[e] = z;
  }
  __syncthreads();
  for (int v = 0; v < 18; v++) {
    for (int e = threadIdx.x; e < 4096; e += 256) {
      int o = e >> 6, tt = e & 63;
      float z = fmaf(g0s[o], xm[tt * 18 + v], fmaf(g1s[o], xm[1152 + tt * 18 + v], bps[o]));
      z = z > 0.0f ? z : 0.0f;
      unsigned short zb = f2bf(z);
      int t = t0 + tt;
      size_t row = ((size_t)(n * 64 + o) * 18 + v) * 272;
      G1[row + 8 + t] = zb;
      if (t < 8) G1[row + t] = 0;
      if (t >= 248) G1[row + t + 16] = 0;
      ldsT[o * 65 + tt] = zb;
    }
    __syncthreads();
    for (int e = threadIdx.x; e < 4096; e += 256) {
      int tt = e >> 6, o = e & 63;  // lanes along o -> 128B contiguous
      Gt1[((size_t)(n * 18 + v) * 272 + t0 + tt) * 64 + o] = ldsT[o * 65 + tt];
    }
    __syncthreads();
  }
  if (blockIdx.y == 3) {
    for (int e = threadIdx.x; e < 18 * 16 * 64; e += 256) {
      int v = e / 1024, r = e % 1024;
      int tg = 256 + r / 64, o = r % 64;
      Gt1[((size_t)(n * 18 + v) * 272 + tg) * 64 + o] = 0;
    }
  }
}

// --------------------------- A-mix on Xt -----------------------------------
template <int CO, int T>
__global__ __launch_bounds__(256, 4) void k_amixX(
    const unsigned short* __restrict__ Xt, unsigned short* __restrict__ Xm,
    const float* __restrict__ Amat) {
  int idx = blockIdx.x * 256 + threadIdx.x;
  int c = idx & (CO - 1);
  int t = (idx / CO) & (T - 1);
  int n = idx / (CO * T);
  const size_t stride = (size_t)T * CO;
  const unsigned short* bp = Xt + (size_t)n * 18 * stride + (size_t)t * CO + c;
  unsigned short* op = Xm + (size_t)n * 18 * stride + (size_t)t * CO + c;
  float xs[18];
#pragma unroll
  for (int w = 0; w < 18; w++) xs[w] = bf2f(bp[w * stride]);
#pragma unroll
  for (int v = 0; v < 18; v++) {
    float z = 0.0f;
#pragma unroll
    for (int w = 0; w < 18; w++) z = fmaf(Amat[v * 18 + w], xs[w], z);
    op[v * stride] = f2bf(z);
  }
}

// --------------------------- channel GEMM -> G + Gt (MFMA) -----------------
// G[n,o,v,8+t] / Gt[n,v,t,o] = relu(s1[o]*(gw·Xm) + b1p[o]); Gt written via
// LDS transpose (coalesced: lanes along c).
template <int CI, int CO, int TIN>
__global__ __launch_bounds__(64, 4) void k_ugemmG(
    const unsigned short* __restrict__ Xm, const unsigned short* __restrict__ Ag,
    const float* __restrict__ s1v, const float* __restrict__ b1p,
    unsigned short* __restrict__ G, unsigned short* __restrict__ Gt) {
  constexpr int NP = 18 * TIN;
  constexpr int Tr = TIN + 16;
  const int n = blockIdx.x;
  const int p0 = blockIdx.y * 32;
  const int otg = blockIdx.z;  // 2 o-tiles of 16
  const int lane = threadIdx.x;
  const int q = lane >> 4, nn = lane & 15;
  constexpr int KC = CI / 32;
  const int v = p0 / TIN;
  const int tb = p0 % TIN;
  __shared__ unsigned short ldsT[32 * 36];  // [t'][o'], pad 36 (8B-aligned rows)
  f32x4 acc[2][2] = {};
  const unsigned short* Xn = Xm + (size_t)n * NP * CI;
  for (int kc = 0; kc < KC; kc++) {
    bf16x8 A[2];
#pragma unroll
    for (int i = 0; i < 2; i++)
      A[i] = *(const bf16x8*)(Ag + (((size_t)(otg * 2 + i) * KC + kc) * 64 + lane) * 8);
#pragma unroll
    for (int u = 0; u < 2; u++) {
      bf16x8 B = *(const bf16x8*)(Xn + (size_t)(p0 + u * 16 + nn) * CI + kc * 32 + q * 8);
#pragma unroll
      for (int i = 0; i < 2; i++)
        acc[i][u] = __builtin_amdgcn_mfma_f32_16x16x32_bf16(A[i], B, acc[i][u], 0, 0, 0);
    }
  }
#pragma unroll
  for (int i = 0; i < 2; i++) {
    int obl = i * 16 + q * 4;       // o-local in [0,32)
    int ob = otg * 32 + obl;
    const float4 s4 = *(const float4*)&s1v[ob];
    const float4 b4 = *(const float4*)&b1p[ob];
#pragma unroll
    for (int u = 0; u < 2; u++) {
      int t = tb + u * 16 + nn;
      unsigned short zb[4];
#pragma unroll
      for (int r = 0; r < 4; r++) {
        float z = fmaf(acc[i][u][r], ((const float*)&s4)[r], ((const float*)&b4)[r]);
        z = z > 0.0f ? z : 0.0f;
        zb[r] = f2bf(z);
        G[((size_t)(n * CO + ob + r) * 18 + v) * Tr + 8 + t] = zb[r];
      }
      *(unsigned long long*)&ldsT[(u * 16 + nn) * 36 + obl] =
          *(const unsigned long long*)zb;
    }
  }
  __syncthreads();
  // Gt write: lanes along c -> 64B lines fully covered
  for (int e = lane; e < 1024; e += 64) {
    int tq = e >> 5, cq2 = e & 31;
    Gt[((size_t)(n * 18 + v) * Tr + tb + tq) * CO + otg * 32 + cq2] = ldsT[tq * 36 + cq2];
  }
  // guards: left/right t-guards of G rows; right t-guard of Gt
  if (tb == 0) {
    int oh = otg * 32 + (lane >> 1), j0 = (lane & 1) * 4;
    size_t row = ((size_t)(n * CO + oh) * 18 + v) * Tr;
#pragma unroll
    for (int j = 0; j < 4; j++) G[row + j0 + j] = 0;
    for (int g = 0; g < 8; g++) {
      int idx = g * 64 + lane;  // 512 = 16t x 32c
      int tg = TIN + (idx >> 5), c = otg * 32 + (idx & 31);
      Gt[((size_t)(n * 18 + v) * Tr + tg) * CO + c] = 0;
    }
  }
  if (tb == TIN - 32) {
    int oh = otg * 32 + (lane >> 1), j0 = (lane & 1) * 4;
    size_t row = ((size_t)(n * CO + oh) * 18 + v) * Tr + 8 + TIN;
#pragma unroll
    for (int j = 0; j < 4; j++) G[row + j0 + j] = 0;
  }
}

// --------------------------- fused conv (MFMA, prefetched) -----------------
// main: taps 0-7, K = 4c x 8taps; tap8: 1x1 over Gt; residual: 1x1 over Xt.
template <int CIN, int CO, int S, int TIN, int TOUT, int OTB, int TB>
__global__ __launch_bounds__(64, 4) void k_conv(
    const unsigned short* __restrict__ G, const unsigned short* __restrict__ Gt,
    const unsigned short* __restrict__ Xt, const float* __restrict__ XB,
    const unsigned short* __restrict__ Ac, const unsigned short* __restrict__ At8,
    const unsigned short* __restrict__ Ar, const float* __restrict__ rwT1,
    const float* __restrict__ beta, unsigned short* __restrict__ Out) {
  constexpr int Tr = TIN + 16;
  constexpr int KC = CO / 4;   // main-loop iterations (4c x 8taps per K=32)
  constexpr int KT8 = CO / 32; // tap-8 iterations
  constexpr int KCR = (CIN >= 32) ? CIN / 32 : 0;
  constexpr int OT2 = CO / (16 * OTB);
  const int n = blockIdx.x;
  const int to_base = blockIdx.y * (16 * TB);
  const int z = blockIdx.z;
  const int otg = z % OT2;
  const int v0 = (z / OT2) * 2;
  const int lane = threadIdx.x;
  const int q = lane >> 4, nn = lane & 15;

  f32x4 acc[OTB][TB][2] = {};

  const unsigned* Gu = (const unsigned*)G;
  // c = kc*4 + q ; per-lane K-run = taps 0..7 = 8 consecutive t from S*to-4
  size_t h_tu[TB][2];
#pragma unroll
  for (int tb = 0; tb < TB; tb++)
#pragma unroll
    for (int u = 0; u < 2; u++) {
      int t0h = S * (to_base + tb * 16 + nn) - 4;
      h_tu[tb][u] = ((size_t)n * CO + q) * (18 * Tr) + (size_t)(v0 + u) * Tr + 8 +
                    (size_t)(long)t0h;
    }

  const unsigned short* Acp = Ac + ((size_t)otg * OTB * KC * 64 + lane) * 8;

  auto loadA = [&](int kc, bf16x8* A) {
#pragma unroll
    for (int i = 0; i < OTB; i++)
      A[i] = *(const bf16x8*)(Acp + ((size_t)i * KC + kc) * 512);
  };
  auto loadB = [&](int kc, bf16x8 (*B)[2]) {
#pragma unroll
    for (int tb = 0; tb < TB; tb++)
#pragma unroll
      for (int u = 0; u < 2; u++) {
        size_t h = h_tu[tb][u] + (size_t)kc * (4 * 18 * Tr);
        union { u32x4 d4; unsigned d[4]; bf16x8 v; } bb;
        if (S == 2) {
          bb.d4 = *(const u32x4*)(Gu + (h >> 1));  // h even for S=2
        } else {
          const unsigned* p = Gu + (h >> 1);
          u32x4 dd = *(const u32x4*)p;
          unsigned d4 = p[4];
          if (h & 1) {
            bb.d[0] = (dd.x >> 16) | (dd.y << 16); bb.d[1] = (dd.y >> 16) | (dd.z << 16);
            bb.d[2] = (dd.z >> 16) | (dd.w << 16); bb.d[3] = (dd.w >> 16) | (d4 << 16);
          } else {
            bb.d4 = dd;
          }
        }
        B[tb][u] = bb.v;
      }
  };

  bf16x8 Acur[OTB], Bcur[TB][2];
  loadA(0, Acur);
  loadB(0, Bcur);
  for (int kc = 0; kc < KC; kc++) {
    bf16x8 Anx[OTB], Bnx[TB][2];
    const int kn = (kc + 1 < KC) ? kc + 1 : kc;
    loadA(kn, Anx);
    loadB(kn, Bnx);
#pragma unroll
    for (int i = 0; i < OTB; i++)
#pragma unroll
      for (int tb = 0; tb < TB; tb++)
#pragma unroll
        for (int u = 0; u < 2; u++)
          acc[i][tb][u] =
              __builtin_amdgcn_mfma_f32_16x16x32_bf16(Acur[i], Bcur[tb][u], acc[i][tb][u],
                                                      0, 0, 0);
#pragma unroll
    for (int i = 0; i < OTB; i++) Acur[i] = Anx[i];
#pragma unroll
    for (int tb = 0; tb < TB; tb++)
#pragma unroll
      for (int u = 0; u < 2; u++) Bcur[tb][u] = Bnx[tb][u];
  }

  // ---- tap 8: 1x1 over Gt at ti = S*to + 4 (right guard covers overrun) ----
  for (int k8 = 0; k8 < KT8; k8++) {
    bf16x8 A[OTB];
#pragma unroll
    for (int i = 0; i < OTB; i++)
      A[i] = *(const bf16x8*)(At8 + (((size_t)(otg * OTB + i) * KT8 + k8) * 64 + lane) * 8);
#pragma unroll
    for (int tb = 0; tb < TB; tb++)
#pragma unroll
      for (int u = 0; u < 2; u++) {
        int ti = S * (to_base + tb * 16 + nn) + 4;
        bf16x8 B = *(const bf16x8*)(Gt + (((size_t)n * 18 + v0 + u) * Tr + ti) * CO +
                                    k8 * 32 + q * 8);
#pragma unroll
        for (int i = 0; i < OTB; i++)
          acc[i][tb][u] =
              __builtin_amdgcn_mfma_f32_16x16x32_bf16(A[i], B, acc[i][tb][u], 0, 0, 0);
      }
  }

  if (CIN >= 32) {
    for (int kcr = 0; kcr < KCR; kcr++) {
      bf16x8 A[OTB];
#pragma unroll
      for (int i = 0; i < OTB; i++)
        A[i] = *(const bf16x8*)(Ar + (((size_t)(otg * OTB + i) * KCR + kcr) * 64 + lane) * 8);
#pragma unroll
      for (int tb = 0; tb < TB; tb++)
#pragma unroll
        for (int u = 0; u < 2; u++) {
          int t = S * (to_base + tb * 16 + nn);
          bf16x8 B = *(const bf16x8*)(Xt + (((size_t)n * 18 + v0 + u) * TIN + t) * CIN +
                                      kcr * 32 + q * 8);
#pragma unroll
          for (int i = 0; i < OTB; i++)
            acc[i][tb][u] =
                __builtin_amdgcn_mfma_f32_16x16x32_bf16(A[i], B, acc[i][tb][u], 0, 0, 0);
        }
    }
  } else {
#pragma unroll
    for (int ci = 0; ci < 2; ci++) {
#pragma unroll
      for (int tb = 0; tb < TB; tb++)
#pragma unroll
        for (int u = 0; u < 2; u++) {
          float xv =
              XB[(((size_t)n * 2 + ci) * 18 + v0 + u) * TIN + S * (to_base + tb * 16 + nn)];
#pragma unroll
          for (int i = 0; i < OTB; i++) {
            const float4 w4 = *(const float4*)&rwT1[ci * CO + (otg * OTB + i) * 16 + q * 4];
            acc[i][tb][u][0] = fmaf(w4.x, xv, acc[i][tb][u][0]);
            acc[i][tb][u][1] = fmaf(w4.y, xv, acc[i][tb][u][1]);
            acc[i][tb][u][2] = fmaf(w4.z, xv, acc[i][tb][u][2]);
            acc[i][tb][u][3] = fmaf(w4.w, xv, acc[i][tb][u][3]);
          }
        }
    }
  }

#pragma unroll
  for (int i = 0; i < OTB; i++) {
    int ob = (otg * OTB + i) * 16 + q * 4;
    const float4 bt = *(const float4*)&beta[ob];
#pragma unroll
    for (int tb = 0; tb < TB; tb++)
#pragma unroll
      for (int u = 0; u < 2; u++) {
        int v = v0 + u, to = to_base + tb * 16 + nn;
#pragma unroll
        for (int r = 0; r < 4; r++) {
          float val = acc[i][tb][u][r] + ((const float*)&bt)[r];
          Out[(((size_t)n * CO + ob + r) * 18 + v) * TOUT + to] =
              f2bf(val > 0.0f ? val : 0.0f);
        }
      }
  }
}

// ------------- EMA smooth (bf16 in) -> bf16 transposed emission ------------
__global__ __launch_bounds__(64) void k_smooth2(
    const unsigned short* __restrict__ X, unsigned short* __restrict__ Xt,
    int CO, int T) {
  __shared__ float tile[64 * 33];
  int n = blockIdx.x, v = blockIdx.y, c0 = blockIdx.z * 64;
  int tid = threadIdx.x;
  float s = 0.0f;
  for (int tc = 0; tc < T; tc += 32) {
    for (int e = tid; e < 64 * 32; e += 64) {
      int cc = e >> 5, tt = e & 31;
      tile[cc * 33 + tt] = bf2f(X[((size_t)(n * CO + c0 + cc) * 18 + v) * T + tc + tt]);
    }
    __syncthreads();
    float* row = &tile[tid * 33];
    int start = 0;
    if (tc == 0) { s = row[0]; start = 1; }
    for (int tt = start; tt < 32; tt++) {
      s = fmaf(0.85f, s, 0.15f * row[tt]);
      row[tt] = s;
    }
    for (int it = 0; it < 32; it++)
      Xt[((size_t)(n * 18 + v) * T + tc + it) * CO + c0 + tid] = f2bf(tile[tid * 33 + it]);
    __syncthreads();
  }
}

// in-place EMA on bf16 rows (block 3); rows contiguous length T.
__global__ __launch_bounds__(64) void k_smooth(unsigned short* __restrict__ X, int T) {
  __shared__ float tile[64 * 33];
  size_t r0 = (size_t)blockIdx.x * 64;
  float s = 0.0f;
  for (int tc = 0; tc < T; tc += 32) {
    for (int e = threadIdx.x; e < 64 * 32; e += 64) {
      int r = e >> 5, tt = e & 31;
      tile[r * 33 + tt] = bf2f(X[(r0 + r) * T + tc + tt]);
    }
    __syncthreads();
    float* row = &tile[threadIdx.x * 33];
    int start = 0;
    if (tc == 0) { s = row[0]; start = 1; }
    for (int tt = start; tt < 32; tt++) {
      s = fmaf(0.85f, s, 0.15f * row[tt]);
      row[tt] = s;
    }
    __syncthreads();
    for (int e = threadIdx.x; e < 64 * 32; e += 64) {
      int r = e >> 5, tt = e & 31;
      X[(r0 + r) * T + tc + tt] = f2bf(tile[r * 33 + tt]);
    }
    __syncthreads();
  }
}

// mean over (v,t)=1152 then 10-way FC.  H:(nc,256,18,64) bf16
__global__ __launch_bounds__(256, 4) void k_poolfc(
    const unsigned short* __restrict__ H, const float* __restrict__ fcw,
    const float* __restrict__ fcb, float* __restrict__ out) {
  int n = blockIdx.x;
  __shared__ float pool[256];
  const unsigned short* row = H + (size_t)(n * 256 + threadIdx.x) * 1152;
  float s = 0.0f;
  for (int i = 0; i < 1152; i += 8) {
    u32x4 d = *(const u32x4*)(row + i);
#pragma unroll
    for (int k = 0; k < 4; k++) {
      unsigned dv = ((const unsigned*)&d)[k];
      s += __builtin_bit_cast(float, dv << 16);
      s += __builtin_bit_cast(float, dv & 0xFFFF0000u);
    }
  }
  pool[threadIdx.x] = s * (1.0f / 1152.0f);
  __syncthreads();
  if (threadIdx.x < 10) {
    float a = fcb[threadIdx.x];
    for (int c = 0; c < 256; c++) a = fmaf(fcw[threadIdx.x * 256 + c], pool[c], a);
    out[n * 10 + threadIdx.x] = a;
  }
}

extern "C" void kernel_launch(void* const* d_in, const int* in_sizes, int n_in,
                              void* d_out, int out_size, void* d_ws, size_t ws_size,
                              hipStream_t stream) {
  const float* x    = (const float*)d_in[0];
  const float* Amat = (const float*)d_in[1];
  const float* dbng = (const float*)d_in[2];
  const float* dbnb = (const float*)d_in[3];
  const float* gw1 = (const float*)d_in[4];   const float* gb1 = (const float*)d_in[5];
  const float* bn1g1 = (const float*)d_in[6]; const float* bn1b1 = (const float*)d_in[7];
  const float* tw1 = (const float*)d_in[8];   const float* tb1 = (const float*)d_in[9];
  const float* bn2g1 = (const float*)d_in[10]; const float* bn2b1 = (const float*)d_in[11];
  const float* rw1 = (const float*)d_in[12];  const float* rb1 = (const float*)d_in[13];
  const float* gw2 = (const float*)d_in[14];  const float* gb2 = (const float*)d_in[15];
  const float* bn1g2 = (const float*)d_in[16]; const float* bn1b2 = (const float*)d_in[17];
  const float* tw2 = (const float*)d_in[18];  const float* tb2 = (const float*)d_in[19];
  const float* bn2g2 = (const float*)d_in[20]; const float* bn2b2 = (const float*)d_in[21];
  const float* rw2 = (const float*)d_in[22];  const float* rb2 = (const float*)d_in[23];
  const float* gw3 = (const float*)d_in[24];  const float* gb3 = (const float*)d_in[25];
  const float* bn1g3 = (const float*)d_in[26]; const float* bn1b3 = (const float*)d_in[27];
  const float* tw3 = (const float*)d_in[28];  const float* tb3 = (const float*)d_in[29];
  const float* bn2g3 = (const float*)d_in[30]; const float* bn2b3 = (const float*)d_in[31];
  const float* rw3 = (const float*)d_in[32];  const float* rb3 = (const float*)d_in[33];
  const float* fcw = (const float*)d_in[34];  const float* fcb = (const float*)d_in[35];
  (void)in_sizes; (void)n_in; (void)out_size;

  // ---- weights region at ws base ----
  float* f = (float*)d_ws;
  float* rwT1  = f;             // 128
  float* beta1 = rwT1 + 128;    // 64
  float* beta2 = beta1 + 64;    // 128
  float* beta3 = beta2 + 128;   // 256
  float* s1v2  = beta3 + 256;   // 128
  float* b1p2  = s1v2 + 128;    // 128
  float* s1v3  = b1p2 + 128;    // 256
  float* b1p3  = s1v3 + 256;    // 256
  // pad to 2048 floats
  unsigned short* H = (unsigned short*)(f + 2048);
  unsigned short* Ac1 = H;                 // 32768   (64^2*8)
  unsigned short* Ac2 = Ac1 + 32768;       // 131072  (128^2*8)
  unsigned short* Ac3 = Ac2 + 131072;      // 524288  (256^2*8)
  unsigned short* At1 = Ac3 + 524288;      // 4096
  unsigned short* At2 = At1 + 4096;        // 16384
  unsigned short* At3 = At2 + 16384;       // 65536
  unsigned short* Ar2 = At3 + 65536;       // 8192
  unsigned short* Ar3 = Ar2 + 8192;        // 32768
  unsigned short* Ag2 = Ar3 + 32768;       // 8192
  unsigned short* Ag3 = Ag2 + 8192;        // 32768
  const size_t WOFFB = 8192 + 856064ULL * 2;  // 1,720,320 bytes (16B aligned)

  // ---- NC = min(40, floor(avail/per_n)) : chunk <= ~200 MB (L3-resident) --
  // per-n bytes: B1 589824 + B2 589824 + XB 36864 + G 1327104 + Gt 1327104
  //            + Xt 589824 + Xm 589824 = 5,050,368
  const size_t PERN = 5050368ULL;
  long long avail = (long long)ws_size - (long long)WOFFB - 256;
  int NC = (avail > 0) ? (int)(avail / (long long)PERN) : 1;
  if (NC > 40) NC = 40;
  if (NC < 1) NC = 1;
  char* wb = (char*)d_ws;
  unsigned short* B1 = (unsigned short*)(wb + WOFFB);
  unsigned short* B2 = B1 + (size_t)NC * 294912;
  float* XB = (float*)((char*)B2 + (size_t)NC * 589824);
  unsigned short* G  = (unsigned short*)((char*)XB + (size_t)NC * 36864);
  unsigned short* Gt = (unsigned short*)((char*)G + (size_t)NC * 1327104);
  unsigned short* Xt = (unsigned short*)((char*)Gt + (size_t)NC * 1327104);
  unsigned short* Xm = Xt + (size_t)NC * 294912;

  // ---- weight prep (idempotent) ----
  k_transpose<<<1, 256, 0, stream>>>(rw1, rwT1, 64, 2);
  k_beta<<<1, 256, 0, stream>>>(bn2g1, bn2b1, tb1, rb1, beta1, 64);
  k_beta<<<1, 256, 0, stream>>>(bn2g2, bn2b2, tb2, rb2, beta2, 128);
  k_beta<<<1, 256, 0, stream>>>(bn2g3, bn2b3, tb3, rb3, beta3, 256);
  k_s1b1<<<1, 256, 0, stream>>>(bn1g2, bn1b2, gb2, s1v2, b1p2, 128);
  k_s1b1<<<1, 256, 0, stream>>>(bn1g3, bn1b3, gb3, s1v3, b1p3, 256);
  k_pack_conv8<<<128, 256, 0, stream>>>(tw1, bn2g1, Ac1, 64);
  k_pack_conv8<<<512, 256, 0, stream>>>(tw2, bn2g2, Ac2, 128);
  k_pack_conv8<<<2048, 256, 0, stream>>>(tw3, bn2g3, Ac3, 256);
  k_pack_tap8<<<16, 256, 0, stream>>>(tw1, bn2g1, At1, 64);
  k_pack_tap8<<<64, 256, 0, stream>>>(tw2, bn2g2, At2, 128);
  k_pack_tap8<<<256, 256, 0, stream>>>(tw3, bn2g3, At3, 256);
  k_pack_k32<<<32, 256, 0, stream>>>(rw2, Ar2, 64, 128);
  k_pack_k32<<<128, 256, 0, stream>>>(rw3, Ar3, 128, 256);
  k_pack_k32<<<32, 256, 0, stream>>>(gw2, Ag2, 64, 128);
  k_pack_k32<<<128, 256, 0, stream>>>(gw3, Ag3, 128, 256);

  // ---- network per N-chunk (ragged) ----
  for (int n0 = 0; n0 < 128; n0 += NC) {
    const int nc = (128 - n0 < NC) ? 128 - n0 : NC;
    // block 1
    k_front1g<<<dim3(nc, 4), 256, 0, stream>>>(
        x + (size_t)n0 * 9216, dbng, dbnb, Amat, gw1, gb1, bn1g1, bn1b1, G, Gt, XB);
    k_conv<2, 64, 1, 256, 256, 4, 2><<<dim3(nc, 8, 9), 64, 0, stream>>>(
        G, Gt, nullptr, XB, Ac1, At1, nullptr, rwT1, beta1, B1);
    k_smooth2<<<dim3(nc, 18, 1), 64, 0, stream>>>(B1, Xt, 64, 256);
    // block 2
    k_amixX<64, 256><<<nc * 64, 256, 0, stream>>>(Xt, Xm, Amat);
    k_ugemmG<64, 128, 256><<<dim3(nc, 144, 4), 64, 0, stream>>>(
        Xm, Ag2, s1v2, b1p2, G, Gt);
    k_conv<64, 128, 2, 256, 128, 4, 2><<<dim3(nc, 4, 18), 64, 0, stream>>>(
        G, Gt, Xt, nullptr, Ac2, At2, Ar2, nullptr, beta2, B2);
    k_smooth2<<<dim3(nc, 18, 2), 64, 0, stream>>>(B2, Xt, 128, 128);
    // block 3 (output reuses B1)
    k_amixX<128, 128><<<nc * 64, 256, 0, stream>>>(Xt, Xm, Amat);
    k_ugemmG<128, 256, 128><<<dim3(nc, 72, 8), 64, 0, stream>>>(
        Xm, Ag3, s1v3, b1p3, G, Gt);
    k_conv<128, 256, 2, 128, 64, 4, 2><<<dim3(nc, 2, 36), 64, 0, stream>>>(
        G, Gt, Xt, nullptr, Ac3, At3, Ar3, nullptr, beta3, B1);
    k_smooth<<<nc * 72, 64, 0, stream>>>(B1, 64);
    // head
    k_poolfc<<<nc, 256, 0, stream>>>(B1, fcw, fcb, (float*)d_out + (size_t)n0 * 10);
  }
}

// Round 16
// 1743.743 us; speedup vs baseline: 1.3043x; 1.0504x over previous
//
#include <hip/hip_runtime.h>
#include <hip/hip_bf16.h>

#define EPS 1e-5f

// ---------------------------------------------------------------------------
// MFMA ST-GCN, R16 = R15 (split-tap conv: taps 0-7 unpadded MFMA K=4cx8taps +
// tap-8 as 1x1 over c-innermost Gt; coalesced Gt emission via LDS transpose)
// with EVEN CHUNKING: R15's NC=40 left a ragged tail chunk of 8 samples (13
// dispatches at ~2 blocks/CU, ~150-250us of near-idle machine). R16 picks the
// minimum chunk count under the L3 budget then equalizes: NC=43 -> 43/43/42.
// Chunk working set ~217MB < 256MB L3 (per-kernel hot set <=170MB).
//   G   : (n, CO, 18, Tr=TIN+16) bf16  t-innermost, 8-half t-guards
//   Gt  : (n, 18, Tr, CO) bf16         c-innermost, right t-guard [TIN,TIN+16)
//   B*  : (n, CO, 18, TOUT) bf16 ; Xt/Xm : (n, 18, T, C) bf16
// fp32 accumulation everywhere.
// ---------------------------------------------------------------------------

typedef __attribute__((ext_vector_type(8))) short bf16x8;
typedef __attribute__((ext_vector_type(4))) float f32x4;
typedef __attribute__((ext_vector_type(4))) unsigned u32x4;

__device__ __forceinline__ unsigned short f2bf(float f) {
  unsigned u = __builtin_bit_cast(unsigned, f);
  u = (u + 0x7FFFu + ((u >> 16) & 1u)) >> 16;  // RNE, finite inputs
  return (unsigned short)u;
}
__device__ __forceinline__ float bf2f(unsigned short h) {
  unsigned u = (unsigned)h << 16;
  return __builtin_bit_cast(float, u);
}

// --------------------------- weight prep -----------------------------------

__global__ __launch_bounds__(256, 4) void k_transpose(
    const float* __restrict__ in, float* __restrict__ out, int rows, int cols) {
  int i = blockIdx.x * 256 + threadIdx.x;
  if (i < rows * cols) {
    int r = i / cols, c = i % cols;
    out[c * rows + r] = in[i];
  }
}

__global__ __launch_bounds__(256, 4) void k_beta(
    const float* __restrict__ bn2g, const float* __restrict__ bn2b,
    const float* __restrict__ tb, const float* __restrict__ rb,
    float* __restrict__ beta, int Co) {
  int o = blockIdx.x * 256 + threadIdx.x;
  if (o < Co)
    beta[o] = bn2g[o] * (1.0f / sqrtf(1.0f + EPS)) * tb[o] + bn2b[o] + rb[o];
}

__global__ __launch_bounds__(256, 4) void k_s1b1(
    const float* __restrict__ bn1g, const float* __restrict__ bn1b,
    const float* __restrict__ gb, float* __restrict__ s1v,
    float* __restrict__ b1p, int Co) {
  int o = blockIdx.x * 256 + threadIdx.x;
  if (o < Co) {
    float s1 = bn1g[o] * (1.0f / sqrtf(1.0f + EPS));
    s1v[o] = s1;
    b1p[o] = fmaf(s1, gb[o], bn1b[o]);
  }
}

// Conv A pack, taps 0-7: out[ot][kc][lane][8]; c = kc*4+q, tap = j (all valid)
__global__ __launch_bounds__(256, 4) void k_pack_conv8(
    const float* __restrict__ tw, const float* __restrict__ bn2g,
    unsigned short* __restrict__ out, int CO) {
  int total = (CO / 16) * (CO / 4) * 512;
  int i = blockIdx.x * 256 + threadIdx.x;
  if (i >= total) return;
  int j = i & 7, lane = (i >> 3) & 63, rest = i >> 9;
  int kc = rest % (CO / 4), ot = rest / (CO / 4);
  int q = lane >> 4, m = lane & 15;
  int c = kc * 4 + q, o = ot * 16 + m;
  out[i] = f2bf(tw[((size_t)o * CO + c) * 9 + j] * bn2g[o] * (1.0f / sqrtf(1.0f + EPS)));
}

// Tap-8 pack (K=c): out[ot][kc][lane][8], c = kc*32+q*8+j
__global__ __launch_bounds__(256, 4) void k_pack_tap8(
    const float* __restrict__ tw, const float* __restrict__ bn2g,
    unsigned short* __restrict__ out, int CO) {
  int total = (CO / 16) * (CO / 32) * 512;
  int i = blockIdx.x * 256 + threadIdx.x;
  if (i >= total) return;
  int j = i & 7, lane = (i >> 3) & 63, rest = i >> 9;
  int kc = rest % (CO / 32), ot = rest / (CO / 32);
  int q = lane >> 4, m = lane & 15;
  int c = kc * 32 + q * 8 + j, o = ot * 16 + m;
  out[i] = f2bf(tw[((size_t)o * CO + c) * 9 + 8] * bn2g[o] * (1.0f / sqrtf(1.0f + EPS)));
}

// K=c pack (residual rw / channel gw): out[ot][kc][lane][8], c = kc*32+q*8+j
__global__ __launch_bounds__(256, 4) void k_pack_k32(
    const float* __restrict__ W, unsigned short* __restrict__ out, int K, int M) {
  int total = (M / 16) * (K / 32) * 512;
  int i = blockIdx.x * 256 + threadIdx.x;
  if (i >= total) return;
  int j = i & 7, lane = (i >> 3) & 63, rest = i >> 9;
  int kc = rest % (K / 32), ot = rest / (K / 32);
  int q = lane >> 4, m = lane & 15;
  int c = kc * 32 + q * 8 + j, o = ot * 16 + m;
  out[i] = f2bf(W[(size_t)o * K + c]);
}

// --------------------------- block 1 front (fused) -------------------------
// data_bn -> A-mix -> 1x1 (2->64) -> BN1+ReLU -> G1 + Gt1 (LDS-transposed,
// coalesced); XB for residual.
__global__ __launch_bounds__(256, 4) void k_front1g(
    const float* __restrict__ x, const float* __restrict__ dbng,
    const float* __restrict__ dbnb, const float* __restrict__ Amat,
    const float* __restrict__ gw, const float* __restrict__ gb,
    const float* __restrict__ bn1g, const float* __restrict__ bn1b,
    unsigned short* __restrict__ G1, unsigned short* __restrict__ Gt1,
    float* __restrict__ xb1) {
  int n = blockIdx.x, t0 = blockIdx.y * 64;
  __shared__ float xb[2304];  // [c][tt][v]
  __shared__ float xm[2304];  // A-mixed
  __shared__ float As[324];
  __shared__ float g0s[64], g1s[64], bps[64];
  __shared__ unsigned short ldsT[64 * 65];  // [o][tt], pad 65
  const float rs = 1.0f / sqrtf(1.0f + EPS);
  for (int e = threadIdx.x; e < 324; e += 256) As[e] = Amat[e];
  if (threadIdx.x < 64) {
    int o = threadIdx.x;
    float s1 = bn1g[o] * rs;
    g0s[o] = gw[o * 2 + 0] * s1;
    g1s[o] = gw[o * 2 + 1] * s1;
    bps[o] = fmaf(s1, gb[o], bn1b[o]);
  }
  for (int e = threadIdx.x; e < 2304; e += 256) {
    int c = e / 1152, r = e % 1152;  // r = tt*18+v
    int v = r % 18;
    xb[e] = x[(n * 2 + c) * 4608 + t0 * 18 + r] * (dbng[c * 18 + v] * rs) + dbnb[c * 18 + v];
  }
  __syncthreads();
  for (int e = threadIdx.x; e < 2304; e += 256) {
    int c = e / 1152, r = e % 1152;
    int v = r / 64, tt = r % 64;
    xb1[((size_t)(n * 2 + c) * 18 + v) * 256 + t0 + tt] = xb[c * 1152 + tt * 18 + v];
  }
  for (int e = threadIdx.x; e < 2304; e += 256) {
    int c = e / 1152, r = e % 1152;
    int tt = r / 18, v = r % 18;
    const float* xr = &xb[c * 1152 + tt * 18];
    float z = 0.0f;
#pragma unroll
    for (int w = 0; w < 18; w++) z = fmaf(As[v * 18 + w], xr[w], z);
    xm[e] = z;
  }
  __syncthreads();
  for (int v = 0; v < 18; v++) {
    for (int e = threadIdx.x; e < 4096; e += 256) {
      int o = e >> 6, tt = e & 63;
      float z = fmaf(g0s[o], xm[tt * 18 + v], fmaf(g1s[o], xm[1152 + tt * 18 + v], bps[o]));
      z = z > 0.0f ? z : 0.0f;
      unsigned short zb = f2bf(z);
      int t = t0 + tt;
      size_t row = ((size_t)(n * 64 + o) * 18 + v) * 272;
      G1[row + 8 + t] = zb;
      if (t < 8) G1[row + t] = 0;
      if (t >= 248) G1[row + t + 16] = 0;
      ldsT[o * 65 + tt] = zb;
    }
    __syncthreads();
    for (int e = threadIdx.x; e < 4096; e += 256) {
      int tt = e >> 6, o = e & 63;  // lanes along o -> 128B contiguous
      Gt1[((size_t)(n * 18 + v) * 272 + t0 + tt) * 64 + o] = ldsT[o * 65 + tt];
    }
    __syncthreads();
  }
  if (blockIdx.y == 3) {
    for (int e = threadIdx.x; e < 18 * 16 * 64; e += 256) {
      int v = e / 1024, r = e % 1024;
      int tg = 256 + r / 64, o = r % 64;
      Gt1[((size_t)(n * 18 + v) * 272 + tg) * 64 + o] = 0;
    }
  }
}

// --------------------------- A-mix on Xt -----------------------------------
template <int CO, int T>
__global__ __launch_bounds__(256, 4) void k_amixX(
    const unsigned short* __restrict__ Xt, unsigned short* __restrict__ Xm,
    const float* __restrict__ Amat) {
  int idx = blockIdx.x * 256 + threadIdx.x;
  int c = idx & (CO - 1);
  int t = (idx / CO) & (T - 1);
  int n = idx / (CO * T);
  const size_t stride = (size_t)T * CO;
  const unsigned short* bp = Xt + (size_t)n * 18 * stride + (size_t)t * CO + c;
  unsigned short* op = Xm + (size_t)n * 18 * stride + (size_t)t * CO + c;
  float xs[18];
#pragma unroll
  for (int w = 0; w < 18; w++) xs[w] = bf2f(bp[w * stride]);
#pragma unroll
  for (int v = 0; v < 18; v++) {
    float z = 0.0f;
#pragma unroll
    for (int w = 0; w < 18; w++) z = fmaf(Amat[v * 18 + w], xs[w], z);
    op[v * stride] = f2bf(z);
  }
}

// --------------------------- channel GEMM -> G + Gt (MFMA) -----------------
// G[n,o,v,8+t] / Gt[n,v,t,o] = relu(s1[o]*(gw·Xm) + b1p[o]); Gt written via
// LDS transpose (coalesced: lanes along c).
template <int CI, int CO, int TIN>
__global__ __launch_bounds__(64, 4) void k_ugemmG(
    const unsigned short* __restrict__ Xm, const unsigned short* __restrict__ Ag,
    const float* __restrict__ s1v, const float* __restrict__ b1p,
    unsigned short* __restrict__ G, unsigned short* __restrict__ Gt) {
  constexpr int NP = 18 * TIN;
  constexpr int Tr = TIN + 16;
  const int n = blockIdx.x;
  const int p0 = blockIdx.y * 32;
  const int otg = blockIdx.z;  // 2 o-tiles of 16
  const int lane = threadIdx.x;
  const int q = lane >> 4, nn = lane & 15;
  constexpr int KC = CI / 32;
  const int v = p0 / TIN;
  const int tb = p0 % TIN;
  __shared__ unsigned short ldsT[32 * 36];  // [t'][o'], pad 36 (8B-aligned rows)
  f32x4 acc[2][2] = {};
  const unsigned short* Xn = Xm + (size_t)n * NP * CI;
  for (int kc = 0; kc < KC; kc++) {
    bf16x8 A[2];
#pragma unroll
    for (int i = 0; i < 2; i++)
      A[i] = *(const bf16x8*)(Ag + (((size_t)(otg * 2 + i) * KC + kc) * 64 + lane) * 8);
#pragma unroll
    for (int u = 0; u < 2; u++) {
      bf16x8 B = *(const bf16x8*)(Xn + (size_t)(p0 + u * 16 + nn) * CI + kc * 32 + q * 8);
#pragma unroll
      for (int i = 0; i < 2; i++)
        acc[i][u] = __builtin_amdgcn_mfma_f32_16x16x32_bf16(A[i], B, acc[i][u], 0, 0, 0);
    }
  }
#pragma unroll
  for (int i = 0; i < 2; i++) {
    int obl = i * 16 + q * 4;       // o-local in [0,32)
    int ob = otg * 32 + obl;
    const float4 s4 = *(const float4*)&s1v[ob];
    const float4 b4 = *(const float4*)&b1p[ob];
#pragma unroll
    for (int u = 0; u < 2; u++) {
      int t = tb + u * 16 + nn;
      unsigned short zb[4];
#pragma unroll
      for (int r = 0; r < 4; r++) {
        float z = fmaf(acc[i][u][r], ((const float*)&s4)[r], ((const float*)&b4)[r]);
        z = z > 0.0f ? z : 0.0f;
        zb[r] = f2bf(z);
        G[((size_t)(n * CO + ob + r) * 18 + v) * Tr + 8 + t] = zb[r];
      }
      *(unsigned long long*)&ldsT[(u * 16 + nn) * 36 + obl] =
          *(const unsigned long long*)zb;
    }
  }
  __syncthreads();
  // Gt write: lanes along c -> 64B lines fully covered
  for (int e = lane; e < 1024; e += 64) {
    int tq = e >> 5, cq2 = e & 31;
    Gt[((size_t)(n * 18 + v) * Tr + tb + tq) * CO + otg * 32 + cq2] = ldsT[tq * 36 + cq2];
  }
  // guards: left/right t-guards of G rows; right t-guard of Gt
  if (tb == 0) {
    int oh = otg * 32 + (lane >> 1), j0 = (lane & 1) * 4;
    size_t row = ((size_t)(n * CO + oh) * 18 + v) * Tr;
#pragma unroll
    for (int j = 0; j < 4; j++) G[row + j0 + j] = 0;
    for (int g = 0; g < 8; g++) {
      int idx = g * 64 + lane;  // 512 = 16t x 32c
      int tg = TIN + (idx >> 5), c = otg * 32 + (idx & 31);
      Gt[((size_t)(n * 18 + v) * Tr + tg) * CO + c] = 0;
    }
  }
  if (tb == TIN - 32) {
    int oh = otg * 32 + (lane >> 1), j0 = (lane & 1) * 4;
    size_t row = ((size_t)(n * CO + oh) * 18 + v) * Tr + 8 + TIN;
#pragma unroll
    for (int j = 0; j < 4; j++) G[row + j0 + j] = 0;
  }
}

// --------------------------- fused conv (MFMA, prefetched) -----------------
// main: taps 0-7, K = 4c x 8taps; tap8: 1x1 over Gt; residual: 1x1 over Xt.
template <int CIN, int CO, int S, int TIN, int TOUT, int OTB, int TB>
__global__ __launch_bounds__(64, 4) void k_conv(
    const unsigned short* __restrict__ G, const unsigned short* __restrict__ Gt,
    const unsigned short* __restrict__ Xt, const float* __restrict__ XB,
    const unsigned short* __restrict__ Ac, const unsigned short* __restrict__ At8,
    const unsigned short* __restrict__ Ar, const float* __restrict__ rwT1,
    const float* __restrict__ beta, unsigned short* __restrict__ Out) {
  constexpr int Tr = TIN + 16;
  constexpr int KC = CO / 4;   // main-loop iterations (4c x 8taps per K=32)
  constexpr int KT8 = CO / 32; // tap-8 iterations
  constexpr int KCR = (CIN >= 32) ? CIN / 32 : 0;
  constexpr int OT2 = CO / (16 * OTB);
  const int n = blockIdx.x;
  const int to_base = blockIdx.y * (16 * TB);
  const int z = blockIdx.z;
  const int otg = z % OT2;
  const int v0 = (z / OT2) * 2;
  const int lane = threadIdx.x;
  const int q = lane >> 4, nn = lane & 15;

  f32x4 acc[OTB][TB][2] = {};

  const unsigned* Gu = (const unsigned*)G;
  // c = kc*4 + q ; per-lane K-run = taps 0..7 = 8 consecutive t from S*to-4
  size_t h_tu[TB][2];
#pragma unroll
  for (int tb = 0; tb < TB; tb++)
#pragma unroll
    for (int u = 0; u < 2; u++) {
      int t0h = S * (to_base + tb * 16 + nn) - 4;
      h_tu[tb][u] = ((size_t)n * CO + q) * (18 * Tr) + (size_t)(v0 + u) * Tr + 8 +
                    (size_t)(long)t0h;
    }

  const unsigned short* Acp = Ac + ((size_t)otg * OTB * KC * 64 + lane) * 8;

  auto loadA = [&](int kc, bf16x8* A) {
#pragma unroll
    for (int i = 0; i < OTB; i++)
      A[i] = *(const bf16x8*)(Acp + ((size_t)i * KC + kc) * 512);
  };
  auto loadB = [&](int kc, bf16x8 (*B)[2]) {
#pragma unroll
    for (int tb = 0; tb < TB; tb++)
#pragma unroll
      for (int u = 0; u < 2; u++) {
        size_t h = h_tu[tb][u] + (size_t)kc * (4 * 18 * Tr);
        union { u32x4 d4; unsigned d[4]; bf16x8 v; } bb;
        if (S == 2) {
          bb.d4 = *(const u32x4*)(Gu + (h >> 1));  // h even for S=2
        } else {
          const unsigned* p = Gu + (h >> 1);
          u32x4 dd = *(const u32x4*)p;
          unsigned d4 = p[4];
          if (h & 1) {
            bb.d[0] = (dd.x >> 16) | (dd.y << 16); bb.d[1] = (dd.y >> 16) | (dd.z << 16);
            bb.d[2] = (dd.z >> 16) | (dd.w << 16); bb.d[3] = (dd.w >> 16) | (d4 << 16);
          } else {
            bb.d4 = dd;
          }
        }
        B[tb][u] = bb.v;
      }
  };

  bf16x8 Acur[OTB], Bcur[TB][2];
  loadA(0, Acur);
  loadB(0, Bcur);
  for (int kc = 0; kc < KC; kc++) {
    bf16x8 Anx[OTB], Bnx[TB][2];
    const int kn = (kc + 1 < KC) ? kc + 1 : kc;
    loadA(kn, Anx);
    loadB(kn, Bnx);
#pragma unroll
    for (int i = 0; i < OTB; i++)
#pragma unroll
      for (int tb = 0; tb < TB; tb++)
#pragma unroll
        for (int u = 0; u < 2; u++)
          acc[i][tb][u] =
              __builtin_amdgcn_mfma_f32_16x16x32_bf16(Acur[i], Bcur[tb][u], acc[i][tb][u],
                                                      0, 0, 0);
#pragma unroll
    for (int i = 0; i < OTB; i++) Acur[i] = Anx[i];
#pragma unroll
    for (int tb = 0; tb < TB; tb++)
#pragma unroll
      for (int u = 0; u < 2; u++) Bcur[tb][u] = Bnx[tb][u];
  }

  // ---- tap 8: 1x1 over Gt at ti = S*to + 4 (right guard covers overrun) ----
  for (int k8 = 0; k8 < KT8; k8++) {
    bf16x8 A[OTB];
#pragma unroll
    for (int i = 0; i < OTB; i++)
      A[i] = *(const bf16x8*)(At8 + (((size_t)(otg * OTB + i) * KT8 + k8) * 64 + lane) * 8);
#pragma unroll
    for (int tb = 0; tb < TB; tb++)
#pragma unroll
      for (int u = 0; u < 2; u++) {
        int ti = S * (to_base + tb * 16 + nn) + 4;
        bf16x8 B = *(const bf16x8*)(Gt + (((size_t)n * 18 + v0 + u) * Tr + ti) * CO +
                                    k8 * 32 + q * 8);
#pragma unroll
        for (int i = 0; i < OTB; i++)
          acc[i][tb][u] =
              __builtin_amdgcn_mfma_f32_16x16x32_bf16(A[i], B, acc[i][tb][u], 0, 0, 0);
      }
  }

  if (CIN >= 32) {
    for (int kcr = 0; kcr < KCR; kcr++) {
      bf16x8 A[OTB];
#pragma unroll
      for (int i = 0; i < OTB; i++)
        A[i] = *(const bf16x8*)(Ar + (((size_t)(otg * OTB + i) * KCR + kcr) * 64 + lane) * 8);
#pragma unroll
      for (int tb = 0; tb < TB; tb++)
#pragma unroll
        for (int u = 0; u < 2; u++) {
          int t = S * (to_base + tb * 16 + nn);
          bf16x8 B = *(const bf16x8*)(Xt + (((size_t)n * 18 + v0 + u) * TIN + t) * CIN +
                                      kcr * 32 + q * 8);
#pragma unroll
          for (int i = 0; i < OTB; i++)
            acc[i][tb][u] =
                __builtin_amdgcn_mfma_f32_16x16x32_bf16(A[i], B, acc[i][tb][u], 0, 0, 0);
        }
    }
  } else {
#pragma unroll
    for (int ci = 0; ci < 2; ci++) {
#pragma unroll
      for (int tb = 0; tb < TB; tb++)
#pragma unroll
        for (int u = 0; u < 2; u++) {
          float xv =
              XB[(((size_t)n * 2 + ci) * 18 + v0 + u) * TIN + S * (to_base + tb * 16 + nn)];
#pragma unroll
          for (int i = 0; i < OTB; i++) {
            const float4 w4 = *(const float4*)&rwT1[ci * CO + (otg * OTB + i) * 16 + q * 4];
            acc[i][tb][u][0] = fmaf(w4.x, xv, acc[i][tb][u][0]);
            acc[i][tb][u][1] = fmaf(w4.y, xv, acc[i][tb][u][1]);
            acc[i][tb][u][2] = fmaf(w4.z, xv, acc[i][tb][u][2]);
            acc[i][tb][u][3] = fmaf(w4.w, xv, acc[i][tb][u][3]);
          }
        }
    }
  }

#pragma unroll
  for (int i = 0; i < OTB; i++) {
    int ob = (otg * OTB + i) * 16 + q * 4;
    const float4 bt = *(const float4*)&beta[ob];
#pragma unroll
    for (int tb = 0; tb < TB; tb++)
#pragma unroll
      for (int u = 0; u < 2; u++) {
        int v = v0 + u, to = to_base + tb * 16 + nn;
#pragma unroll
        for (int r = 0; r < 4; r++) {
          float val = acc[i][tb][u][r] + ((const float*)&bt)[r];
          Out[(((size_t)n * CO + ob + r) * 18 + v) * TOUT + to] =
              f2bf(val > 0.0f ? val : 0.0f);
        }
      }
  }
}

// ------------- EMA smooth (bf16 in) -> bf16 transposed emission ------------
__global__ __launch_bounds__(64) void k_smooth2(
    const unsigned short* __restrict__ X, unsigned short* __restrict__ Xt,
    int CO, int T) {
  __shared__ float tile[64 * 33];
  int n = blockIdx.x, v = blockIdx.y, c0 = blockIdx.z * 64;
  int tid = threadIdx.x;
  float s = 0.0f;
  for (int tc = 0; tc < T; tc += 32) {
    for (int e = tid; e < 64 * 32; e += 64) {
      int cc = e >> 5, tt = e & 31;
      tile[cc * 33 + tt] = bf2f(X[((size_t)(n * CO + c0 + cc) * 18 + v) * T + tc + tt]);
    }
    __syncthreads();
    float* row = &tile[tid * 33];
    int start = 0;
    if (tc == 0) { s = row[0]; start = 1; }
    for (int tt = start; tt < 32; tt++) {
      s = fmaf(0.85f, s, 0.15f * row[tt]);
      row[tt] = s;
    }
    for (int it = 0; it < 32; it++)
      Xt[((size_t)(n * 18 + v) * T + tc + it) * CO + c0 + tid] = f2bf(tile[tid * 33 + it]);
    __syncthreads();
  }
}

// in-place EMA on bf16 rows (block 3); rows contiguous length T.
__global__ __launch_bounds__(64) void k_smooth(unsigned short* __restrict__ X, int T) {
  __shared__ float tile[64 * 33];
  size_t r0 = (size_t)blockIdx.x * 64;
  float s = 0.0f;
  for (int tc = 0; tc < T; tc += 32) {
    for (int e = threadIdx.x; e < 64 * 32; e += 64) {
      int r = e >> 5, tt = e & 31;
      tile[r * 33 + tt] = bf2f(X[(r0 + r) * T + tc + tt]);
    }
    __syncthreads();
    float* row = &tile[threadIdx.x * 33];
    int start = 0;
    if (tc == 0) { s = row[0]; start = 1; }
    for (int tt = start; tt < 32; tt++) {
      s = fmaf(0.85f, s, 0.15f * row[tt]);
      row[tt] = s;
    }
    __syncthreads();
    for (int e = threadIdx.x; e < 64 * 32; e += 64) {
      int r = e >> 5, tt = e & 31;
      X[(r0 + r) * T + tc + tt] = f2bf(tile[r * 33 + tt]);
    }
    __syncthreads();
  }
}

// mean over (v,t)=1152 then 10-way FC.  H:(nc,256,18,64) bf16
__global__ __launch_bounds__(256, 4) void k_poolfc(
    const unsigned short* __restrict__ H, const float* __restrict__ fcw,
    const float* __restrict__ fcb, float* __restrict__ out) {
  int n = blockIdx.x;
  __shared__ float pool[256];
  const unsigned short* row = H + (size_t)(n * 256 + threadIdx.x) * 1152;
  float s = 0.0f;
  for (int i = 0; i < 1152; i += 8) {
    u32x4 d = *(const u32x4*)(row + i);
#pragma unroll
    for (int k = 0; k < 4; k++) {
      unsigned dv = ((const unsigned*)&d)[k];
      s += __builtin_bit_cast(float, dv << 16);
      s += __builtin_bit_cast(float, dv & 0xFFFF0000u);
    }
  }
  pool[threadIdx.x] = s * (1.0f / 1152.0f);
  __syncthreads();
  if (threadIdx.x < 10) {
    float a = fcb[threadIdx.x];
    for (int c = 0; c < 256; c++) a = fmaf(fcw[threadIdx.x * 256 + c], pool[c], a);
    out[n * 10 + threadIdx.x] = a;
  }
}

extern "C" void kernel_launch(void* const* d_in, const int* in_sizes, int n_in,
                              void* d_out, int out_size, void* d_ws, size_t ws_size,
                              hipStream_t stream) {
  const float* x    = (const float*)d_in[0];
  const float* Amat = (const float*)d_in[1];
  const float* dbng = (const float*)d_in[2];
  const float* dbnb = (const float*)d_in[3];
  const float* gw1 = (const float*)d_in[4];   const float* gb1 = (const float*)d_in[5];
  const float* bn1g1 = (const float*)d_in[6]; const float* bn1b1 = (const float*)d_in[7];
  const float* tw1 = (const float*)d_in[8];   const float* tb1 = (const float*)d_in[9];
  const float* bn2g1 = (const float*)d_in[10]; const float* bn2b1 = (const float*)d_in[11];
  const float* rw1 = (const float*)d_in[12];  const float* rb1 = (const float*)d_in[13];
  const float* gw2 = (const float*)d_in[14];  const float* gb2 = (const float*)d_in[15];
  const float* bn1g2 = (const float*)d_in[16]; const float* bn1b2 = (const float*)d_in[17];
  const float* tw2 = (const float*)d_in[18];  const float* tb2 = (const float*)d_in[19];
  const float* bn2g2 = (const float*)d_in[20]; const float* bn2b2 = (const float*)d_in[21];
  const float* rw2 = (const float*)d_in[22];  const float* rb2 = (const float*)d_in[23];
  const float* gw3 = (const float*)d_in[24];  const float* gb3 = (const float*)d_in[25];
  const float* bn1g3 = (const float*)d_in[26]; const float* bn1b3 = (const float*)d_in[27];
  const float* tw3 = (const float*)d_in[28];  const float* tb3 = (const float*)d_in[29];
  const float* bn2g3 = (const float*)d_in[30]; const float* bn2b3 = (const float*)d_in[31];
  const float* rw3 = (const float*)d_in[32];  const float* rb3 = (const float*)d_in[33];
  const float* fcw = (const float*)d_in[34];  const float* fcb = (const float*)d_in[35];
  (void)in_sizes; (void)n_in; (void)out_size;

  // ---- weights region at ws base ----
  float* f = (float*)d_ws;
  float* rwT1  = f;             // 128
  float* beta1 = rwT1 + 128;    // 64
  float* beta2 = beta1 + 64;    // 128
  float* beta3 = beta2 + 128;   // 256
  float* s1v2  = beta3 + 256;   // 128
  float* b1p2  = s1v2 + 128;    // 128
  float* s1v3  = b1p2 + 128;    // 256
  float* b1p3  = s1v3 + 256;    // 256
  // pad to 2048 floats
  unsigned short* H = (unsigned short*)(f + 2048);
  unsigned short* Ac1 = H;                 // 32768   (64^2*8)
  unsigned short* Ac2 = Ac1 + 32768;       // 131072  (128^2*8)
  unsigned short* Ac3 = Ac2 + 131072;      // 524288  (256^2*8)
  unsigned short* At1 = Ac3 + 524288;      // 4096
  unsigned short* At2 = At1 + 4096;        // 16384
  unsigned short* At3 = At2 + 16384;       // 65536
  unsigned short* Ar2 = At3 + 65536;       // 8192
  unsigned short* Ar3 = Ar2 + 8192;        // 32768
  unsigned short* Ag2 = Ar3 + 32768;       // 8192
  unsigned short* Ag3 = Ag2 + 8192;        // 32768
  const size_t WOFFB = 8192 + 856064ULL * 2;  // 1,720,320 bytes (16B aligned)

  // ---- NC: minimize chunk count under L3 budget, then equalize ----
  // per-n bytes: B1 589824 + B2 589824 + XB 36864 + G 1327104 + Gt 1327104
  //            + Xt 589824 + Xm 589824 = 5,050,368
  // cap 43 -> 3 chunks of 43/43/42 (~217 MB working set, L3-resident;
  // R15's 40 left a tail chunk of 8 = ~200us of near-idle dispatches).
  const size_t PERN = 5050368ULL;
  long long avail = (long long)ws_size - (long long)WOFFB - 256;
  int NC = (avail > 0) ? (int)(avail / (long long)PERN) : 1;
  if (NC > 43) NC = 43;
  if (NC < 1) NC = 1;
  {
    int nch = (128 + NC - 1) / NC;
    NC = (128 + nch - 1) / nch;  // equalize chunk sizes (43,43,42 at cap)
  }
  char* wb = (char*)d_ws;
  unsigned short* B1 = (unsigned short*)(wb + WOFFB);
  unsigned short* B2 = B1 + (size_t)NC * 294912;
  float* XB = (float*)((char*)B2 + (size_t)NC * 589824);
  unsigned short* G  = (unsigned short*)((char*)XB + (size_t)NC * 36864);
  unsigned short* Gt = (unsigned short*)((char*)G + (size_t)NC * 1327104);
  unsigned short* Xt = (unsigned short*)((char*)Gt + (size_t)NC * 1327104);
  unsigned short* Xm = Xt + (size_t)NC * 294912;

  // ---- weight prep (idempotent) ----
  k_transpose<<<1, 256, 0, stream>>>(rw1, rwT1, 64, 2);
  k_beta<<<1, 256, 0, stream>>>(bn2g1, bn2b1, tb1, rb1, beta1, 64);
  k_beta<<<1, 256, 0, stream>>>(bn2g2, bn2b2, tb2, rb2, beta2, 128);
  k_beta<<<1, 256, 0, stream>>>(bn2g3, bn2b3, tb3, rb3, beta3, 256);
  k_s1b1<<<1, 256, 0, stream>>>(bn1g2, bn1b2, gb2, s1v2, b1p2, 128);
  k_s1b1<<<1, 256, 0, stream>>>(bn1g3, bn1b3, gb3, s1v3, b1p3, 256);
  k_pack_conv8<<<128, 256, 0, stream>>>(tw1, bn2g1, Ac1, 64);
  k_pack_conv8<<<512, 256, 0, stream>>>(tw2, bn2g2, Ac2, 128);
  k_pack_conv8<<<2048, 256, 0, stream>>>(tw3, bn2g3, Ac3, 256);
  k_pack_tap8<<<16, 256, 0, stream>>>(tw1, bn2g1, At1, 64);
  k_pack_tap8<<<64, 256, 0, stream>>>(tw2, bn2g2, At2, 128);
  k_pack_tap8<<<256, 256, 0, stream>>>(tw3, bn2g3, At3, 256);
  k_pack_k32<<<32, 256, 0, stream>>>(rw2, Ar2, 64, 128);
  k_pack_k32<<<128, 256, 0, stream>>>(rw3, Ar3, 128, 256);
  k_pack_k32<<<32, 256, 0, stream>>>(gw2, Ag2, 64, 128);
  k_pack_k32<<<128, 256, 0, stream>>>(gw3, Ag3, 128, 256);

  // ---- network per N-chunk (even) ----
  for (int n0 = 0; n0 < 128; n0 += NC) {
    const int nc = (128 - n0 < NC) ? 128 - n0 : NC;
    // block 1
    k_front1g<<<dim3(nc, 4), 256, 0, stream>>>(
        x + (size_t)n0 * 9216, dbng, dbnb, Amat, gw1, gb1, bn1g1, bn1b1, G, Gt, XB);
    k_conv<2, 64, 1, 256, 256, 4, 2><<<dim3(nc, 8, 9), 64, 0, stream>>>(
        G, Gt, nullptr, XB, Ac1, At1, nullptr, rwT1, beta1, B1);
    k_smooth2<<<dim3(nc, 18, 1), 64, 0, stream>>>(B1, Xt, 64, 256);
    // block 2
    k_amixX<64, 256><<<nc * 64, 256, 0, stream>>>(Xt, Xm, Amat);
    k_ugemmG<64, 128, 256><<<dim3(nc, 144, 4), 64, 0, stream>>>(
        Xm, Ag2, s1v2, b1p2, G, Gt);
    k_conv<64, 128, 2, 256, 128, 4, 2><<<dim3(nc, 4, 18), 64, 0, stream>>>(
        G, Gt, Xt, nullptr, Ac2, At2, Ar2, nullptr, beta2, B2);
    k_smooth2<<<dim3(nc, 18, 2), 64, 0, stream>>>(B2, Xt, 128, 128);
    // block 3 (output reuses B1)
    k_amixX<128, 128><<<nc * 64, 256, 0, stream>>>(Xt, Xm, Amat);
    k_ugemmG<128, 256, 128><<<dim3(nc, 72, 8), 64, 0, stream>>>(
        Xm, Ag3, s1v3, b1p3, G, Gt);
    k_conv<128, 256, 2, 128, 64, 4, 2><<<dim3(nc, 2, 36), 64, 0, stream>>>(
        G, Gt, Xt, nullptr, Ac3, At3, Ar3, nullptr, beta3, B1);
    k_smooth<<<nc * 72, 64, 0, stream>>>(B1, 64);
    // head
    k_poolfc<<<nc, 256, 0, stream>>>(B1, fcw, fcb, (float*)d_out + (size_t)n0 * 10);
  }
}